// Round 11
// baseline (655.320 us; speedup 1.0000x reference)
//
#include <hip/hip_runtime.h>
#include <hip/hip_bf16.h>
#include <math.h>

#define N_NODES 20000
#define N_EDGES 320000
#define NODE_DIM 64
#define EDGE_DIM 32
#define HID 128
#define HEADS 4
#define HC1 512   // HEADS*HID
#define NEG_SLOPE 0.2f

typedef __attribute__((ext_vector_type(8))) short bf16x8;
typedef __attribute__((ext_vector_type(4))) float f32x4;

__device__ __forceinline__ unsigned short f2b(float f) {
  unsigned u = __float_as_uint(f);
  unsigned r = (u + 0x7fffu + ((u >> 16) & 1u)) >> 16;
  return (unsigned short)r;
}
__device__ __forceinline__ float b2f(unsigned short b) {
  return __uint_as_float(((unsigned)b) << 16);
}

// ---------------- CSR build + degree sort (LPT) ----------------
__global__ void deg_count_kernel(const int* __restrict__ dsts, int* __restrict__ deg) {
  int e = blockIdx.x * blockDim.x + threadIdx.x;
  if (e < N_EDGES) atomicAdd(&deg[dsts[e]], 1);
}

__global__ void hist_kernel(const int* __restrict__ deg, int* __restrict__ hist) {
  int n = blockIdx.x * blockDim.x + threadIdx.x;
  if (n >= N_NODES) return;
  int k = deg[n]; k = k > 63 ? 63 : k;
  atomicAdd(&hist[63 - k], 1);           // descending degree order (LPT)
}

__global__ void histscan_kernel(const int* __restrict__ hist, int* __restrict__ cursor2) {
  int lane = threadIdx.x;                 // 64 threads
  int v = hist[lane];
  int s = v;
  #pragma unroll
  for (int o = 1; o < 64; o <<= 1) { int u = __shfl_up(s, o); if (lane >= o) s += u; }
  cursor2[lane] = s - v;                  // exclusive prefix
}

__global__ void permscatter_kernel(const int* __restrict__ deg, int* __restrict__ cursor2,
                                   int* __restrict__ perm) {
  int n = blockIdx.x * blockDim.x + threadIdx.x;
  if (n >= N_NODES) return;
  int k = deg[n]; k = k > 63 ? 63 : k;
  int pos = atomicAdd(&cursor2[63 - k], 1);
  perm[pos] = n;
}

__global__ __launch_bounds__(1024) void scan_kernel(
    const int* __restrict__ deg, int* __restrict__ offs, int* __restrict__ cursor)
{
  __shared__ int part[1024];
  int t = threadIdx.x;
  const int C = 20;                 // 1024*20 = 20480 >= N_NODES
  int base = t * C;
  int loc[C]; int s = 0;
  #pragma unroll
  for (int i = 0; i < C; i++) { loc[i] = s; int idx = base + i; s += (idx < N_NODES) ? deg[idx] : 0; }
  part[t] = s;
  __syncthreads();
  for (int off = 1; off < 1024; off <<= 1) {
    int v = (t >= off) ? part[t - off] : 0;
    __syncthreads();
    part[t] += v;
    __syncthreads();
  }
  int pbase = (t > 0) ? part[t - 1] : 0;
  #pragma unroll
  for (int i = 0; i < C; i++) {
    int idx = base + i;
    if (idx < N_NODES) { int o = pbase + loc[i]; offs[idx] = o; cursor[idx] = o; }
  }
  if (t == 1023) offs[N_NODES] = part[1023];
}

__global__ void scatter_kernel(const int* __restrict__ dsts, int* __restrict__ cursor,
                               int* __restrict__ csr) {
  int e = blockIdx.x * blockDim.x + threadIdx.x;
  if (e >= N_EDGES) return;
  int pos = atomicAdd(&cursor[dsts[e]], 1);
  csr[pos] = e;
}

// ---------------- linear1 ----------------
__global__ __launch_bounds__(256) void linear1_kernel(
    const float* __restrict__ x, const float* __restrict__ Wl,
    const float* __restrict__ bl, const float* __restrict__ Wr,
    const float* __restrict__ br, float* __restrict__ xl, float* __restrict__ xr)
{
  __shared__ float xsT[NODE_DIM][16];
  int n0 = blockIdx.x * 16;
  int t = threadIdx.x;
  {
    int flat = t * 4;
    int i = flat >> 6, k = flat & 63;
    float4 v = *(const float4*)&x[(size_t)(n0 + i) * NODE_DIM + k];
    xsT[k + 0][i] = v.x; xsT[k + 1][i] = v.y; xsT[k + 2][i] = v.z; xsT[k + 3][i] = v.w;
  }
  __syncthreads();
  for (int m = 0; m < 2; m++) {
    const float* W  = m ? Wr : Wl;
    const float* bb = m ? br : bl;
    float* out = m ? xr : xl;
    for (int jh = 0; jh < 2; jh++) {
      int j = t + jh * 256;
      float acc[16];
      #pragma unroll
      for (int i = 0; i < 16; i++) acc[i] = 0.f;
      for (int k = 0; k < NODE_DIM; k++) {
        float w = W[k * HC1 + j];
        float xv[16];
        *(float4*)&xv[0]  = *(const float4*)&xsT[k][0];
        *(float4*)&xv[4]  = *(const float4*)&xsT[k][4];
        *(float4*)&xv[8]  = *(const float4*)&xsT[k][8];
        *(float4*)&xv[12] = *(const float4*)&xsT[k][12];
        #pragma unroll
        for (int i = 0; i < 16; i++) acc[i] = fmaf(xv[i], w, acc[i]);
      }
      float bj = bb[j];
      #pragma unroll
      for (int i = 0; i < 16; i++) out[(size_t)(n0 + i) * HC1 + j] = acc[i] + bj;
    }
  }
}

// ---------------- fused layer 1 (MFMA ee-GEMM; half-split; LPT perm) ----------------
// block = 512 threads = 8 waves = 8 nodes x ONE half (half = blockIdx&1).
// ee = ea@We via mfma_f32_16x16x32_bf16 (K=32 exactly): A = 4 real edge rows
// (+12 garbage rows, row-independent so harmless), B = WtT tiles from LDS.
// C/D layout (verified): col=lane&15, row=(lane>>4)*4+reg -> lanes 0-15 hold
// the 4 real edges in regs 0-3; scattered to per-wave ee_s, tail reads it.
template<bool H1BF>
__global__ __launch_bounds__(512, 2) void fused1_kernel(
    const float* __restrict__ ea, const int* __restrict__ srcs,
    const float* __restrict__ We, const float* __restrict__ att,
    const float* __restrict__ xl, const float* __restrict__ xr,
    const float* __restrict__ bias, const int* __restrict__ offs,
    const int* __restrict__ csr, const int* __restrict__ perm,
    void* __restrict__ h1out)
{
  __shared__ short WtT[256 * 40];        // 20.0KB: half's We, transposed [ch][k], bf16, rows padded to 40
  __shared__ short easb[8][16 * 40];     // 10KB: per-wave A tile (16 rows x 40), only rows 0-3 written
  __shared__ float ee_s[8][4][260];      // 33.3KB: per-wave ee result, 4 edges x 256ch (+pad)
  int t = threadIdx.x;
  int half = blockIdx.x & 1;
  // stage We half transposed->bf16 (coalesced read over ch)
  for (int i = t; i < EDGE_DIM * 256; i += 512) {
    int k = i >> 8, c = i & 255;
    WtT[c * 40 + k] = (short)f2b(We[(size_t)k * HC1 + half * 256 + c]);
  }
  __syncthreads();
  int wave = t >> 6, lane = t & 63;
  int n = perm[(blockIdx.x >> 1) * 8 + wave];   // 2500 groups * 8 = 20000 exact
  int Cl = lane * 4;                 // channel within the half
  int C = half * 256 + Cl;           // global channel
  float at4[4], xr4[4];
  *(float4*)at4 = *(const float4*)&att[C];
  *(float4*)xr4 = *(const float4*)&xr[(size_t)n * HC1 + C];
  float o4[4] = {0.f,0.f,0.f,0.f};
  float mx = 8.0f, dn = 0.f;
  int beg = offs[n], end = offs[n + 1];
  int ev = 0, sv = 0;
  if (lane < 4 && beg + lane < end) { ev = csr[beg + lane]; sv = srcs[ev]; }
  for (int i0 = beg; i0 < end; i0 += 4) {
    int nv = end - i0; if (nv > 4) nv = 4;
    int sarr[4];
    #pragma unroll
    for (int j = 0; j < 4; j++) sarr[j] = __shfl(sv, j);
    // issue xl gathers FIRST (latency hides under staging + MFMA below)
    float xv0[4], xv1[4], xv2[4], xv3[4];
    #pragma unroll
    for (int c = 0; c < 4; c++) { xv0[c] = 0.f; xv1[c] = 0.f; xv2[c] = 0.f; xv3[c] = 0.f; }
    if (0 < nv) *(float4*)xv0 = *(const float4*)&xl[(size_t)sarr[0] * HC1 + C];
    if (1 < nv) *(float4*)xv1 = *(const float4*)&xl[(size_t)sarr[1] * HC1 + C];
    if (2 < nv) *(float4*)xv2 = *(const float4*)&xl[(size_t)sarr[2] * HC1 + C];
    if (3 < nv) *(float4*)xv3 = *(const float4*)&xl[(size_t)sarr[3] * HC1 + C];
    // stage the chunk's 4 ea rows as bf16 into A-layout (lanes 0-15: edge=lane>>2, kq=lane&3)
    {
      int me = __shfl(ev, (lane >> 2) & 3);
      if (lane < 16) {
        int q = lane & 3;
        float4 u0 = *(const float4*)&ea[(size_t)me * EDGE_DIM + q * 8];
        float4 u1 = *(const float4*)&ea[(size_t)me * EDGE_DIM + q * 8 + 4];
        short* dst = &easb[wave][(lane >> 2) * 40 + q * 8];
        dst[0] = (short)f2b(u0.x); dst[1] = (short)f2b(u0.y);
        dst[2] = (short)f2b(u0.z); dst[3] = (short)f2b(u0.w);
        dst[4] = (short)f2b(u1.x); dst[5] = (short)f2b(u1.y);
        dst[6] = (short)f2b(u1.z); dst[7] = (short)f2b(u1.w);
      }
    }
    // prefetch next chunk's indices
    if (lane < 4 && i0 + 4 + lane < end) { ev = csr[i0 + 4 + lane]; sv = srcs[ev]; }
    // MFMA: 16 tiles of 16 ch, K=32 in one instruction each
    bf16x8 afrag = *(bf16x8*)&easb[wave][(lane & 15) * 40 + (lane >> 4) * 8];
    #pragma unroll 4
    for (int tt = 0; tt < 16; tt++) {
      bf16x8 bfrag = *(bf16x8*)&WtT[(tt * 16 + (lane & 15)) * 40 + (lane >> 4) * 8];
      f32x4 cz = {0.f, 0.f, 0.f, 0.f};
      f32x4 cv = __builtin_amdgcn_mfma_f32_16x16x32_bf16(afrag, bfrag, cz, 0, 0, 0);
      if (lane < 16) {
        #pragma unroll
        for (int r = 0; r < 4; r++) ee_s[wave][r][tt * 16 + lane] = cv[r];
      }
    }
    // tail: read a4 from ee_s; logits; softmax; accumulate (unchanged structure)
    float a40[4], a41[4], a42[4], a43[4];
    *(float4*)a40 = *(const float4*)&ee_s[wave][0][Cl];
    *(float4*)a41 = *(const float4*)&ee_s[wave][1][Cl];
    *(float4*)a42 = *(const float4*)&ee_s[wave][2][Cl];
    *(float4*)a43 = *(const float4*)&ee_s[wave][3][Cl];
    float pl[4];
    #pragma unroll
    for (int j = 0; j < 4; j++) {
      const float* aj  = (j == 0) ? a40 : (j == 1) ? a41 : (j == 2) ? a42 : a43;
      const float* xvj = (j == 0) ? xv0 : (j == 1) ? xv1 : (j == 2) ? xv2 : xv3;
      float s = 0.f;
      #pragma unroll
      for (int c = 0; c < 4; c++) {
        float z = aj[c] + xvj[c] + xr4[c];
        float zm = z > 0.f ? z : NEG_SLOPE * z;
        s = fmaf(zm, at4[c], s);
      }
      #pragma unroll
      for (int o = 1; o <= 16; o <<= 1) s += __shfl_xor(s, o);
      pl[j] = (j < nv) ? s : -3.0e38f;
    }
    float cm = fmaxf(fmaxf(pl[0], pl[1]), fmaxf(pl[2], pl[3]));
    float mn = fmaxf(mx, cm);
    if (__any(mn > mx + 8.f)) {
      float fs = __expf(mx - mn);
      dn *= fs;
      #pragma unroll
      for (int c = 0; c < 4; c++) o4[c] *= fs;
      mx = mn;
    }
    float p[4];
    #pragma unroll
    for (int j = 0; j < 4; j++) p[j] = __expf(pl[j] - mx);
    dn += (p[0] + p[1]) + (p[2] + p[3]);
    #pragma unroll
    for (int c = 0; c < 4; c++) {
      o4[c] += (p[0] * xv0[c] + p[1] * xv1[c]) + (p[2] * xv2[c] + p[3] * xv3[c]);
    }
  }
  float iv = dn > 0.f ? 1.f / dn : 0.f;
  float r[4];
  #pragma unroll
  for (int c = 0; c < 4; c++) {
    float v = o4[c] * iv + bias[C + c];
    r[c] = v > 0.f ? v : 0.f;            // relu after conv1
  }
  if (H1BF) {
    unsigned short* hb = (unsigned short*)h1out;
    ushort4 u;
    u.x = f2b(r[0]); u.y = f2b(r[1]); u.z = f2b(r[2]); u.w = f2b(r[3]);
    *(ushort4*)&hb[(size_t)n * HC1 + C] = u;
  } else {
    float* hf = (float*)h1out;
    *(float4*)&hf[(size_t)n * HC1 + C] = *(float4*)r;
  }
}

// ---------------- linear2 ----------------
template<bool INBF>
__global__ __launch_bounds__(256) void linear2_kernel(
    const void* __restrict__ hin_, const float* __restrict__ Wl,
    const float* __restrict__ bl, const float* __restrict__ Wr,
    const float* __restrict__ br, float* __restrict__ xl, float* __restrict__ xr)
{
  __shared__ float xsT[HC1][16];   // 32KB
  int n0 = blockIdx.x * 16;
  int t = threadIdx.x;
  for (int r = 0; r < 8; r++) {
    int flat = (t + r * 256) * 4;
    int i = flat >> 9, k = flat & 511;
    float4 v;
    if (INBF) {
      const unsigned short* hb = (const unsigned short*)hin_;
      ushort4 u = *(const ushort4*)&hb[(size_t)(n0 + i) * HC1 + k];
      v.x = b2f(u.x); v.y = b2f(u.y); v.z = b2f(u.z); v.w = b2f(u.w);
    } else {
      const float* hf = (const float*)hin_;
      v = *(const float4*)&hf[(size_t)(n0 + i) * HC1 + k];
    }
    xsT[k + 0][i] = v.x; xsT[k + 1][i] = v.y; xsT[k + 2][i] = v.z; xsT[k + 3][i] = v.w;
  }
  __syncthreads();
  int m = t >> 7, j = t & 127;
  const float* W = m ? Wr : Wl;
  float bj = (m ? br : bl)[j];
  float* out = m ? xr : xl;
  float acc[16];
  #pragma unroll
  for (int i = 0; i < 16; i++) acc[i] = 0.f;
  for (int k = 0; k < HC1; k++) {
    float w = W[k * HID + j];
    float xv[16];
    *(float4*)&xv[0]  = *(const float4*)&xsT[k][0];
    *(float4*)&xv[4]  = *(const float4*)&xsT[k][4];
    *(float4*)&xv[8]  = *(const float4*)&xsT[k][8];
    *(float4*)&xv[12] = *(const float4*)&xsT[k][12];
    #pragma unroll
    for (int i = 0; i < 16; i++) acc[i] = fmaf(xv[i], w, acc[i]);
  }
  #pragma unroll
  for (int i = 0; i < 16; i++) out[(size_t)(n0 + i) * HID + j] = acc[i] + bj;
}

// ---------------- fused layer 2 (unchanged from R10) ----------------
__global__ __launch_bounds__(512, 3) void fused2_kernel(
    const float* __restrict__ ea, const int* __restrict__ srcs,
    const float* __restrict__ We, const float* __restrict__ att,
    const float* __restrict__ xl, const float* __restrict__ xr,
    const float* __restrict__ bias, const int* __restrict__ offs,
    const int* __restrict__ csr, float* __restrict__ h2out)
{
  __shared__ float Ws[EDGE_DIM * HID];      // 16KB
  __shared__ float eas[8][8][EDGE_DIM];     // 8KB
  int t = threadIdx.x;
  for (int i = t * 4; i < EDGE_DIM * HID; i += 2048)
    *(float4*)&Ws[i] = *(const float4*)&We[i];
  __syncthreads();
  int wave = t >> 6, lane = t & 63;
  int n = blockIdx.x * 8 + wave;
  int c = lane * 2;
  float2 atv = *(const float2*)&att[c];
  float2 xrv = *(const float2*)&xr[(size_t)n * HID + c];
  float oa = 0.f, ob = 0.f;
  float m = 8.0f, d = 0.f;
  int beg = offs[n], end = offs[n + 1];
  int ev = 0, sv = 0;
  if (lane < 8 && beg + lane < end) { ev = csr[beg + lane]; sv = srcs[ev]; }
  for (int i0 = beg; i0 < end; i0 += 8) {
    int nv = end - i0; if (nv > 8) nv = 8;
    int sarr[8];
    #pragma unroll
    for (int j = 0; j < 8; j++) sarr[j] = __shfl(sv, j);
    float2 xv[8];
    #pragma unroll
    for (int j = 0; j < 8; j++) {
      if (j < nv) xv[j] = *(const float2*)&xl[(size_t)sarr[j] * HID + c];
      else { xv[j].x = 0.f; xv[j].y = 0.f; }
    }
    {
      int mye = __shfl(ev, lane >> 3);
      float4 eav = *(const float4*)&ea[(size_t)mye * EDGE_DIM + (lane & 7) * 4];
      *(float4*)&eas[wave][lane >> 3][(lane & 7) * 4] = eav;
    }
    if (lane < 8 && i0 + 8 + lane < end) { ev = csr[i0 + 8 + lane]; sv = srcs[ev]; }
    float aa[8], ab[8];
    #pragma unroll
    for (int j = 0; j < 8; j++) { aa[j] = 0.f; ab[j] = 0.f; }
    #pragma unroll 2
    for (int kk = 0; kk < 8; kk++) {
      float av[8][4];
      #pragma unroll
      for (int j = 0; j < 8; j++)
        *(float4*)&av[j][0] = *(const float4*)&eas[wave][j][kk * 4];
      #pragma unroll
      for (int dk = 0; dk < 4; dk++) {
        float2 wv = *(const float2*)&Ws[(kk * 4 + dk) * HID + c];
        #pragma unroll
        for (int j = 0; j < 8; j++) {
          aa[j] = fmaf(av[j][dk], wv.x, aa[j]);
          ab[j] = fmaf(av[j][dk], wv.y, ab[j]);
        }
      }
    }
    float pl[8];
    #pragma unroll
    for (int j = 0; j < 8; j++) {
      float za = aa[j] + xv[j].x + xrv.x;
      float zb = ab[j] + xv[j].y + xrv.y;
      za = za > 0.f ? za : NEG_SLOPE * za;
      zb = zb > 0.f ? zb : NEG_SLOPE * zb;
      float s = za * atv.x + zb * atv.y;
      #pragma unroll
      for (int o = 1; o < 64; o <<= 1) s += __shfl_xor(s, o);
      pl[j] = (j < nv) ? s : -3.0e38f;
    }
    float cm = fmaxf(fmaxf(fmaxf(pl[0], pl[1]), fmaxf(pl[2], pl[3])),
                     fmaxf(fmaxf(pl[4], pl[5]), fmaxf(pl[6], pl[7])));
    float mn = fmaxf(m, cm);
    if (__any(mn > m + 8.f)) {
      float fs = __expf(m - mn);
      d *= fs; oa *= fs; ob *= fs;
      m = mn;
    }
    float p[8];
    #pragma unroll
    for (int j = 0; j < 8; j++) p[j] = __expf(pl[j] - m);
    d += ((p[0] + p[1]) + (p[2] + p[3])) + ((p[4] + p[5]) + (p[6] + p[7]));
    #pragma unroll
    for (int j = 0; j < 8; j++) {
      oa = fmaf(p[j], xv[j].x, oa);
      ob = fmaf(p[j], xv[j].y, ob);
    }
  }
  float invd = d > 0.f ? 1.f / d : 0.f;
  float2 o2 = make_float2(oa * invd + bias[c], ob * invd + bias[c + 1]); // no relu after conv2
  *(float2*)&h2out[(size_t)n * HID + c] = o2;
}

// ---------------- MLP head ----------------
__global__ __launch_bounds__(256) void head_kernel(
    const float* __restrict__ h2, const float* __restrict__ Wh1,
    const float* __restrict__ bh1, const float* __restrict__ Wh2,
    const float* __restrict__ bh2, float* __restrict__ out)
{
  __shared__ float hs[16][HID];   // 8KB
  __shared__ float ts[16][64];    // 4KB
  int n0 = blockIdx.x * 16;
  int t = threadIdx.x;
  for (int r = 0; r < 2; r++) {
    int flat = (t + r * 256) * 4; // 2048 floats
    int i = flat >> 7, k = flat & 127;
    *(float4*)&hs[i][k] = *(const float4*)&h2[(size_t)(n0 + i) * HID + k];
  }
  __syncthreads();
  int j = t & 63, g = t >> 6;
  float acc[4];
  #pragma unroll
  for (int q = 0; q < 4; q++) acc[q] = 0.f;
  for (int k = 0; k < HID; k++) {
    float w = Wh1[k * 64 + j];
    #pragma unroll
    for (int q = 0; q < 4; q++) acc[q] = fmaf(hs[g + 4 * q][k], w, acc[q]);
  }
  float bj = bh1[j];
  #pragma unroll
  for (int q = 0; q < 4; q++) {
    float v = acc[q] + bj;
    ts[g + 4 * q][j] = v > 0.f ? v : 0.f;
  }
  __syncthreads();
  if (t < 32) {
    int nl = t >> 1, k = t & 1;
    float acc2 = bh2[k];
    for (int jj = 0; jj < 64; jj++) acc2 = fmaf(ts[nl][jj], Wh2[jj * 2 + k], acc2);
    out[(size_t)(n0 + nl) * 2 + k] = acc2;
  }
}

extern "C" void kernel_launch(void* const* d_in, const int* in_sizes, int n_in,
                              void* d_out, int out_size, void* d_ws, size_t ws_size,
                              hipStream_t stream)
{
  (void)in_sizes; (void)n_in; (void)out_size;
  const float* x    = (const float*)d_in[0];
  const int* eidx   = (const int*)d_in[1];
  const float* ea   = (const float*)d_in[2];
  const float* Wl1  = (const float*)d_in[3];
  const float* bl1  = (const float*)d_in[4];
  const float* Wr1  = (const float*)d_in[5];
  const float* br1  = (const float*)d_in[6];
  const float* We1  = (const float*)d_in[7];
  const float* att1 = (const float*)d_in[8];
  const float* bias1= (const float*)d_in[9];
  const float* Wl2  = (const float*)d_in[10];
  const float* bl2  = (const float*)d_in[11];
  const float* Wr2  = (const float*)d_in[12];
  const float* br2  = (const float*)d_in[13];
  const float* We2  = (const float*)d_in[14];
  const float* att2 = (const float*)d_in[15];
  const float* bias2= (const float*)d_in[16];
  const float* Wh1  = (const float*)d_in[17];
  const float* bh1  = (const float*)d_in[18];
  const float* Wh2  = (const float*)d_in[19];
  const float* bh2  = (const float*)d_in[20];
  const int* srcs = eidx;
  const int* dsts = eidx + N_EDGES;
  float* out = (float*)d_out;

  const size_t szBig = (size_t)N_NODES * HC1 * sizeof(float);
  auto aln = [](size_t b) { return (b + 511) & ~(size_t)511; };
  size_t smallSz = aln((size_t)N_NODES * 4) * 3 + aln((size_t)(N_NODES + 1) * 4)
                 + aln((size_t)N_EDGES * 4) + aln(64 * 4) * 2;
  size_t needF = aln(szBig) * 3 + smallSz + 4096;
  bool useBF = ws_size < needF;

  char* p = (char*)d_ws;
  auto alloc = [&](size_t bytes) { char* q = p; p += (bytes + 511) & ~(size_t)511; return q; };
  float* xl1 = (float*)alloc(szBig);
  float* xr1 = (float*)alloc(szBig);          // reused for xl2/xr2 after fused1
  void*  h1  = (void*)alloc(useBF ? szBig / 2 : szBig);
  int* deg    = (int*)alloc((size_t)N_NODES * 4);
  int* offs   = (int*)alloc((size_t)(N_NODES + 1) * 4);
  int* cursor = (int*)alloc((size_t)N_NODES * 4);
  int* csr    = (int*)alloc((size_t)N_EDGES * 4);
  int* hist   = (int*)alloc(64 * 4);
  int* cursor2= (int*)alloc(64 * 4);
  int* perm   = (int*)alloc((size_t)N_NODES * 4);
  float* xl2 = xr1;
  float* xr2 = xr1 + (size_t)N_NODES * HID;
  float* h2  = xl1;                            // xl1 region dead after fused1

  hipMemsetAsync(deg, 0, (size_t)N_NODES * 4, stream);
  hipMemsetAsync(hist, 0, 64 * 4, stream);
  hipLaunchKernelGGL(deg_count_kernel, dim3((N_EDGES + 255) / 256), dim3(256), 0, stream, dsts, deg);
  hipLaunchKernelGGL(hist_kernel, dim3((N_NODES + 255) / 256), dim3(256), 0, stream, deg, hist);
  hipLaunchKernelGGL(histscan_kernel, dim3(1), dim3(64), 0, stream, hist, cursor2);
  hipLaunchKernelGGL(permscatter_kernel, dim3((N_NODES + 255) / 256), dim3(256), 0, stream,
                     deg, cursor2, perm);
  hipLaunchKernelGGL(scan_kernel, dim3(1), dim3(1024), 0, stream, deg, offs, cursor);
  hipLaunchKernelGGL(scatter_kernel, dim3((N_EDGES + 255) / 256), dim3(256), 0, stream, dsts, cursor, csr);
  hipLaunchKernelGGL(linear1_kernel, dim3(N_NODES / 16), dim3(256), 0, stream,
                     x, Wl1, bl1, Wr1, br1, xl1, xr1);
  // fused1: grid = (N/8 node-groups) x 2 halves
  if (useBF)
    hipLaunchKernelGGL((fused1_kernel<true>), dim3((N_NODES / 8) * 2), dim3(512), 0, stream,
                       ea, srcs, We1, att1, xl1, xr1, bias1, offs, csr, perm, h1);
  else
    hipLaunchKernelGGL((fused1_kernel<false>), dim3((N_NODES / 8) * 2), dim3(512), 0, stream,
                       ea, srcs, We1, att1, xl1, xr1, bias1, offs, csr, perm, h1);
  if (useBF)
    hipLaunchKernelGGL((linear2_kernel<true>), dim3(N_NODES / 16), dim3(256), 0, stream,
                       h1, Wl2, bl2, Wr2, br2, xl2, xr2);
  else
    hipLaunchKernelGGL((linear2_kernel<false>), dim3(N_NODES / 16), dim3(256), 0, stream,
                       h1, Wl2, bl2, Wr2, br2, xl2, xr2);
  hipLaunchKernelGGL(fused2_kernel, dim3(N_NODES / 8), dim3(512), 0, stream,
                     ea, srcs, We2, att2, xl2, xr2, bias2, offs, csr, h2);
  hipLaunchKernelGGL(head_kernel, dim3(N_NODES / 16), dim3(256), 0, stream,
                     h2, Wh1, bh1, Wh2, bh2, out);
}

// Round 12
// 605.388 us; speedup vs baseline: 1.0825x; 1.0825x over previous
//
#include <hip/hip_runtime.h>
#include <hip/hip_bf16.h>
#include <math.h>

#define N_NODES 20000
#define N_EDGES 320000
#define NODE_DIM 64
#define EDGE_DIM 32
#define HID 128
#define HEADS 4
#define HC1 512   // HEADS*HID
#define NEG_SLOPE 0.2f

typedef __attribute__((ext_vector_type(8))) short bf16x8;
typedef __attribute__((ext_vector_type(4))) float f32x4;

__device__ __forceinline__ unsigned short f2b(float f) {
  unsigned u = __float_as_uint(f);
  unsigned r = (u + 0x7fffu + ((u >> 16) & 1u)) >> 16;
  return (unsigned short)r;
}
__device__ __forceinline__ float b2f(unsigned short b) {
  return __uint_as_float(((unsigned)b) << 16);
}

// ---------------- CSR build ----------------
__global__ void deg_count_kernel(const int* __restrict__ dsts, int* __restrict__ deg) {
  int e = blockIdx.x * blockDim.x + threadIdx.x;
  if (e < N_EDGES) atomicAdd(&deg[dsts[e]], 1);
}

__global__ __launch_bounds__(1024) void scan_kernel(
    const int* __restrict__ deg, int* __restrict__ offs, int* __restrict__ cursor)
{
  __shared__ int part[1024];
  int t = threadIdx.x;
  const int C = 20;                 // 1024*20 = 20480 >= N_NODES
  int base = t * C;
  int loc[C]; int s = 0;
  #pragma unroll
  for (int i = 0; i < C; i++) { loc[i] = s; int idx = base + i; s += (idx < N_NODES) ? deg[idx] : 0; }
  part[t] = s;
  __syncthreads();
  for (int off = 1; off < 1024; off <<= 1) {
    int v = (t >= off) ? part[t - off] : 0;
    __syncthreads();
    part[t] += v;
    __syncthreads();
  }
  int pbase = (t > 0) ? part[t - 1] : 0;
  #pragma unroll
  for (int i = 0; i < C; i++) {
    int idx = base + i;
    if (idx < N_NODES) { int o = pbase + loc[i]; offs[idx] = o; cursor[idx] = o; }
  }
  if (t == 1023) offs[N_NODES] = part[1023];
}

__global__ void scatter_kernel(const int* __restrict__ dsts, int* __restrict__ cursor,
                               int* __restrict__ csr) {
  int e = blockIdx.x * blockDim.x + threadIdx.x;
  if (e >= N_EDGES) return;
  int pos = atomicAdd(&cursor[dsts[e]], 1);
  csr[pos] = e;
}

// ---------------- linear1 ----------------
__global__ __launch_bounds__(256) void linear1_kernel(
    const float* __restrict__ x, const float* __restrict__ Wl,
    const float* __restrict__ bl, const float* __restrict__ Wr,
    const float* __restrict__ br, float* __restrict__ xl, float* __restrict__ xr)
{
  __shared__ float xsT[NODE_DIM][16];
  int n0 = blockIdx.x * 16;
  int t = threadIdx.x;
  {
    int flat = t * 4;
    int i = flat >> 6, k = flat & 63;
    float4 v = *(const float4*)&x[(size_t)(n0 + i) * NODE_DIM + k];
    xsT[k + 0][i] = v.x; xsT[k + 1][i] = v.y; xsT[k + 2][i] = v.z; xsT[k + 3][i] = v.w;
  }
  __syncthreads();
  for (int m = 0; m < 2; m++) {
    const float* W  = m ? Wr : Wl;
    const float* bb = m ? br : bl;
    float* out = m ? xr : xl;
    for (int jh = 0; jh < 2; jh++) {
      int j = t + jh * 256;
      float acc[16];
      #pragma unroll
      for (int i = 0; i < 16; i++) acc[i] = 0.f;
      for (int k = 0; k < NODE_DIM; k++) {
        float w = W[k * HC1 + j];
        float xv[16];
        *(float4*)&xv[0]  = *(const float4*)&xsT[k][0];
        *(float4*)&xv[4]  = *(const float4*)&xsT[k][4];
        *(float4*)&xv[8]  = *(const float4*)&xsT[k][8];
        *(float4*)&xv[12] = *(const float4*)&xsT[k][12];
        #pragma unroll
        for (int i = 0; i < 16; i++) acc[i] = fmaf(xv[i], w, acc[i]);
      }
      float bj = bb[j];
      #pragma unroll
      for (int i = 0; i < 16; i++) out[(size_t)(n0 + i) * HC1 + j] = acc[i] + bj;
    }
  }
}

// ---------------- fused layer 1 (MFMA, W-in-registers; half-split) ----------------
// block = 512 threads = 8 waves = 8 nodes x ONE half (half = blockIdx&1).
// D[ch][edge] = sum_k WtT[ch][k] * ea[edge][k]: A = WtT tiles (PRELOADED into
// 16 reg fragments, constant), B = 4-edge ea tile (1 LDS read/chunk).
// C/D layout: col=lane&15 (edge), row=(lane>>4)*4+reg (channel-in-tile).
// Lanes with (lane&15)<4 hold real edges; scatter contiguous float4 to ee_s.
template<bool H1BF>
__global__ __launch_bounds__(512, 2) void fused1_kernel(
    const float* __restrict__ ea, const int* __restrict__ srcs,
    const float* __restrict__ We, const float* __restrict__ att,
    const float* __restrict__ xl, const float* __restrict__ xr,
    const float* __restrict__ bias, const int* __restrict__ offs,
    const int* __restrict__ csr, void* __restrict__ h1out)
{
  __shared__ short WtT[256 * 40];        // 20.0KB: half's We, transposed [ch][k], bf16
  __shared__ short easb[8][16 * 40];     // 10KB: per-wave B tile (16 edge rows x 40), rows 0-3 real
  __shared__ float ee_s[8][4][260];      // 33.3KB: per-wave ee result, 4 edges x 256ch (+pad)
  int t = threadIdx.x;
  int half = blockIdx.x & 1;
  // stage We half transposed->bf16 (coalesced read over ch)
  for (int i = t; i < EDGE_DIM * 256; i += 512) {
    int k = i >> 8, c = i & 255;
    WtT[c * 40 + k] = (short)f2b(We[(size_t)k * HC1 + half * 256 + c]);
  }
  __syncthreads();
  int wave = t >> 6, lane = t & 63;
  int l15 = lane & 15, l16 = lane >> 4;
  // preload the 16 A fragments (constant WtT tiles) into registers
  bf16x8 af[16];
  #pragma unroll
  for (int tt = 0; tt < 16; tt++)
    af[tt] = *(bf16x8*)&WtT[(tt * 16 + l15) * 40 + l16 * 8];
  int n = (blockIdx.x >> 1) * 8 + wave;   // 2500 groups * 8 = 20000 exact
  int Cl = lane * 4;                 // channel within the half
  int C = half * 256 + Cl;           // global channel
  float at4[4], xr4[4];
  *(float4*)at4 = *(const float4*)&att[C];
  *(float4*)xr4 = *(const float4*)&xr[(size_t)n * HC1 + C];
  float o4[4] = {0.f,0.f,0.f,0.f};
  float mx = 8.0f, dn = 0.f;
  int beg = offs[n], end = offs[n + 1];
  int ev = 0, sv = 0;
  if (lane < 4 && beg + lane < end) { ev = csr[beg + lane]; sv = srcs[ev]; }
  for (int i0 = beg; i0 < end; i0 += 4) {
    int nv = end - i0; if (nv > 4) nv = 4;
    int sarr[4];
    #pragma unroll
    for (int j = 0; j < 4; j++) sarr[j] = __shfl(sv, j);
    // issue xl gathers FIRST (latency hides under staging + MFMA below)
    float xv0[4], xv1[4], xv2[4], xv3[4];
    #pragma unroll
    for (int c = 0; c < 4; c++) { xv0[c] = 0.f; xv1[c] = 0.f; xv2[c] = 0.f; xv3[c] = 0.f; }
    if (0 < nv) *(float4*)xv0 = *(const float4*)&xl[(size_t)sarr[0] * HC1 + C];
    if (1 < nv) *(float4*)xv1 = *(const float4*)&xl[(size_t)sarr[1] * HC1 + C];
    if (2 < nv) *(float4*)xv2 = *(const float4*)&xl[(size_t)sarr[2] * HC1 + C];
    if (3 < nv) *(float4*)xv3 = *(const float4*)&xl[(size_t)sarr[3] * HC1 + C];
    // stage the chunk's 4 ea rows as bf16 (lanes 0-15: edge=lane>>2, quarter q=lane&3)
    {
      int me = __shfl(ev, (lane >> 2) & 3);
      if (lane < 16) {
        int q = lane & 3;
        float4 u0 = *(const float4*)&ea[(size_t)me * EDGE_DIM + q * 8];
        float4 u1 = *(const float4*)&ea[(size_t)me * EDGE_DIM + q * 8 + 4];
        short* dst = &easb[wave][(lane >> 2) * 40 + q * 8];
        dst[0] = (short)f2b(u0.x); dst[1] = (short)f2b(u0.y);
        dst[2] = (short)f2b(u0.z); dst[3] = (short)f2b(u0.w);
        dst[4] = (short)f2b(u1.x); dst[5] = (short)f2b(u1.y);
        dst[6] = (short)f2b(u1.z); dst[7] = (short)f2b(u1.w);
      }
    }
    // prefetch next chunk's indices
    if (lane < 4 && i0 + 4 + lane < end) { ev = csr[i0 + 4 + lane]; sv = srcs[ev]; }
    // one B-frag read; 16 MFMAs with register-resident A
    bf16x8 bfrag = *(bf16x8*)&easb[wave][l15 * 40 + l16 * 8];
    #pragma unroll
    for (int tt = 0; tt < 16; tt++) {
      f32x4 cz = {0.f, 0.f, 0.f, 0.f};
      f32x4 cv = __builtin_amdgcn_mfma_f32_16x16x32_bf16(af[tt], bfrag, cz, 0, 0, 0);
      if (l15 < 4) *(float4*)&ee_s[wave][l15][tt * 16 + l16 * 4] = *(float4*)&cv;
    }
    // tail: read a4 from ee_s; logits; softmax; accumulate
    float a40[4], a41[4], a42[4], a43[4];
    *(float4*)a40 = *(const float4*)&ee_s[wave][0][Cl];
    *(float4*)a41 = *(const float4*)&ee_s[wave][1][Cl];
    *(float4*)a42 = *(const float4*)&ee_s[wave][2][Cl];
    *(float4*)a43 = *(const float4*)&ee_s[wave][3][Cl];
    float pl[4];
    #pragma unroll
    for (int j = 0; j < 4; j++) {
      const float* aj  = (j == 0) ? a40 : (j == 1) ? a41 : (j == 2) ? a42 : a43;
      const float* xvj = (j == 0) ? xv0 : (j == 1) ? xv1 : (j == 2) ? xv2 : xv3;
      float s = 0.f;
      #pragma unroll
      for (int c = 0; c < 4; c++) {
        float z = aj[c] + xvj[c] + xr4[c];
        float zm = z > 0.f ? z : NEG_SLOPE * z;
        s = fmaf(zm, at4[c], s);
      }
      #pragma unroll
      for (int o = 1; o <= 16; o <<= 1) s += __shfl_xor(s, o);
      pl[j] = (j < nv) ? s : -3.0e38f;
    }
    float cm = fmaxf(fmaxf(pl[0], pl[1]), fmaxf(pl[2], pl[3]));
    float mn = fmaxf(mx, cm);
    if (__any(mn > mx + 8.f)) {
      float fs = __expf(mx - mn);
      dn *= fs;
      #pragma unroll
      for (int c = 0; c < 4; c++) o4[c] *= fs;
      mx = mn;
    }
    float p[4];
    #pragma unroll
    for (int j = 0; j < 4; j++) p[j] = __expf(pl[j] - mx);
    dn += (p[0] + p[1]) + (p[2] + p[3]);
    #pragma unroll
    for (int c = 0; c < 4; c++) {
      o4[c] += (p[0] * xv0[c] + p[1] * xv1[c]) + (p[2] * xv2[c] + p[3] * xv3[c]);
    }
  }
  float iv = dn > 0.f ? 1.f / dn : 0.f;
  float r[4];
  #pragma unroll
  for (int c = 0; c < 4; c++) {
    float v = o4[c] * iv + bias[C + c];
    r[c] = v > 0.f ? v : 0.f;            // relu after conv1
  }
  if (H1BF) {
    unsigned short* hb = (unsigned short*)h1out;
    ushort4 u;
    u.x = f2b(r[0]); u.y = f2b(r[1]); u.z = f2b(r[2]); u.w = f2b(r[3]);
    *(ushort4*)&hb[(size_t)n * HC1 + C] = u;
  } else {
    float* hf = (float*)h1out;
    *(float4*)&hf[(size_t)n * HC1 + C] = *(float4*)r;
  }
}

// ---------------- linear2 ----------------
template<bool INBF>
__global__ __launch_bounds__(256) void linear2_kernel(
    const void* __restrict__ hin_, const float* __restrict__ Wl,
    const float* __restrict__ bl, const float* __restrict__ Wr,
    const float* __restrict__ br, float* __restrict__ xl, float* __restrict__ xr)
{
  __shared__ float xsT[HC1][16];   // 32KB
  int n0 = blockIdx.x * 16;
  int t = threadIdx.x;
  for (int r = 0; r < 8; r++) {
    int flat = (t + r * 256) * 4;
    int i = flat >> 9, k = flat & 511;
    float4 v;
    if (INBF) {
      const unsigned short* hb = (const unsigned short*)hin_;
      ushort4 u = *(const ushort4*)&hb[(size_t)(n0 + i) * HC1 + k];
      v.x = b2f(u.x); v.y = b2f(u.y); v.z = b2f(u.z); v.w = b2f(u.w);
    } else {
      const float* hf = (const float*)hin_;
      v = *(const float4*)&hf[(size_t)(n0 + i) * HC1 + k];
    }
    xsT[k + 0][i] = v.x; xsT[k + 1][i] = v.y; xsT[k + 2][i] = v.z; xsT[k + 3][i] = v.w;
  }
  __syncthreads();
  int m = t >> 7, j = t & 127;
  const float* W = m ? Wr : Wl;
  float bj = (m ? br : bl)[j];
  float* out = m ? xr : xl;
  float acc[16];
  #pragma unroll
  for (int i = 0; i < 16; i++) acc[i] = 0.f;
  for (int k = 0; k < HC1; k++) {
    float w = W[k * HID + j];
    float xv[16];
    *(float4*)&xv[0]  = *(const float4*)&xsT[k][0];
    *(float4*)&xv[4]  = *(const float4*)&xsT[k][4];
    *(float4*)&xv[8]  = *(const float4*)&xsT[k][8];
    *(float4*)&xv[12] = *(const float4*)&xsT[k][12];
    #pragma unroll
    for (int i = 0; i < 16; i++) acc[i] = fmaf(xv[i], w, acc[i]);
  }
  #pragma unroll
  for (int i = 0; i < 16; i++) out[(size_t)(n0 + i) * HID + j] = acc[i] + bj;
}

// ---------------- fused layer 2 (unchanged) ----------------
__global__ __launch_bounds__(512, 3) void fused2_kernel(
    const float* __restrict__ ea, const int* __restrict__ srcs,
    const float* __restrict__ We, const float* __restrict__ att,
    const float* __restrict__ xl, const float* __restrict__ xr,
    const float* __restrict__ bias, const int* __restrict__ offs,
    const int* __restrict__ csr, float* __restrict__ h2out)
{
  __shared__ float Ws[EDGE_DIM * HID];      // 16KB
  __shared__ float eas[8][8][EDGE_DIM];     // 8KB
  int t = threadIdx.x;
  for (int i = t * 4; i < EDGE_DIM * HID; i += 2048)
    *(float4*)&Ws[i] = *(const float4*)&We[i];
  __syncthreads();
  int wave = t >> 6, lane = t & 63;
  int n = blockIdx.x * 8 + wave;
  int c = lane * 2;
  float2 atv = *(const float2*)&att[c];
  float2 xrv = *(const float2*)&xr[(size_t)n * HID + c];
  float oa = 0.f, ob = 0.f;
  float m = 8.0f, d = 0.f;
  int beg = offs[n], end = offs[n + 1];
  int ev = 0, sv = 0;
  if (lane < 8 && beg + lane < end) { ev = csr[beg + lane]; sv = srcs[ev]; }
  for (int i0 = beg; i0 < end; i0 += 8) {
    int nv = end - i0; if (nv > 8) nv = 8;
    int sarr[8];
    #pragma unroll
    for (int j = 0; j < 8; j++) sarr[j] = __shfl(sv, j);
    float2 xv[8];
    #pragma unroll
    for (int j = 0; j < 8; j++) {
      if (j < nv) xv[j] = *(const float2*)&xl[(size_t)sarr[j] * HID + c];
      else { xv[j].x = 0.f; xv[j].y = 0.f; }
    }
    {
      int mye = __shfl(ev, lane >> 3);
      float4 eav = *(const float4*)&ea[(size_t)mye * EDGE_DIM + (lane & 7) * 4];
      *(float4*)&eas[wave][lane >> 3][(lane & 7) * 4] = eav;
    }
    if (lane < 8 && i0 + 8 + lane < end) { ev = csr[i0 + 8 + lane]; sv = srcs[ev]; }
    float aa[8], ab[8];
    #pragma unroll
    for (int j = 0; j < 8; j++) { aa[j] = 0.f; ab[j] = 0.f; }
    #pragma unroll 2
    for (int kk = 0; kk < 8; kk++) {
      float av[8][4];
      #pragma unroll
      for (int j = 0; j < 8; j++)
        *(float4*)&av[j][0] = *(const float4*)&eas[wave][j][kk * 4];
      #pragma unroll
      for (int dk = 0; dk < 4; dk++) {
        float2 wv = *(const float2*)&Ws[(kk * 4 + dk) * HID + c];
        #pragma unroll
        for (int j = 0; j < 8; j++) {
          aa[j] = fmaf(av[j][dk], wv.x, aa[j]);
          ab[j] = fmaf(av[j][dk], wv.y, ab[j]);
        }
      }
    }
    float pl[8];
    #pragma unroll
    for (int j = 0; j < 8; j++) {
      float za = aa[j] + xv[j].x + xrv.x;
      float zb = ab[j] + xv[j].y + xrv.y;
      za = za > 0.f ? za : NEG_SLOPE * za;
      zb = zb > 0.f ? zb : NEG_SLOPE * zb;
      float s = za * atv.x + zb * atv.y;
      #pragma unroll
      for (int o = 1; o < 64; o <<= 1) s += __shfl_xor(s, o);
      pl[j] = (j < nv) ? s : -3.0e38f;
    }
    float cm = fmaxf(fmaxf(fmaxf(pl[0], pl[1]), fmaxf(pl[2], pl[3])),
                     fmaxf(fmaxf(pl[4], pl[5]), fmaxf(pl[6], pl[7])));
    float mn = fmaxf(m, cm);
    if (__any(mn > m + 8.f)) {
      float fs = __expf(m - mn);
      d *= fs; oa *= fs; ob *= fs;
      m = mn;
    }
    float p[8];
    #pragma unroll
    for (int j = 0; j < 8; j++) p[j] = __expf(pl[j] - m);
    d += ((p[0] + p[1]) + (p[2] + p[3])) + ((p[4] + p[5]) + (p[6] + p[7]));
    #pragma unroll
    for (int j = 0; j < 8; j++) {
      oa = fmaf(p[j], xv[j].x, oa);
      ob = fmaf(p[j], xv[j].y, ob);
    }
  }
  float invd = d > 0.f ? 1.f / d : 0.f;
  float2 o2 = make_float2(oa * invd + bias[c], ob * invd + bias[c + 1]); // no relu after conv2
  *(float2*)&h2out[(size_t)n * HID + c] = o2;
}

// ---------------- MLP head ----------------
__global__ __launch_bounds__(256) void head_kernel(
    const float* __restrict__ h2, const float* __restrict__ Wh1,
    const float* __restrict__ bh1, const float* __restrict__ Wh2,
    const float* __restrict__ bh2, float* __restrict__ out)
{
  __shared__ float hs[16][HID];   // 8KB
  __shared__ float ts[16][64];    // 4KB
  int n0 = blockIdx.x * 16;
  int t = threadIdx.x;
  for (int r = 0; r < 2; r++) {
    int flat = (t + r * 256) * 4; // 2048 floats
    int i = flat >> 7, k = flat & 127;
    *(float4*)&hs[i][k] = *(const float4*)&h2[(size_t)(n0 + i) * HID + k];
  }
  __syncthreads();
  int j = t & 63, g = t >> 6;
  float acc[4];
  #pragma unroll
  for (int q = 0; q < 4; q++) acc[q] = 0.f;
  for (int k = 0; k < HID; k++) {
    float w = Wh1[k * 64 + j];
    #pragma unroll
    for (int q = 0; q < 4; q++) acc[q] = fmaf(hs[g + 4 * q][k], w, acc[q]);
  }
  float bj = bh1[j];
  #pragma unroll
  for (int q = 0; q < 4; q++) {
    float v = acc[q] + bj;
    ts[g + 4 * q][j] = v > 0.f ? v : 0.f;
  }
  __syncthreads();
  if (t < 32) {
    int nl = t >> 1, k = t & 1;
    float acc2 = bh2[k];
    for (int jj = 0; jj < 64; jj++) acc2 = fmaf(ts[nl][jj], Wh2[jj * 2 + k], acc2);
    out[(size_t)(n0 + nl) * 2 + k] = acc2;
  }
}

extern "C" void kernel_launch(void* const* d_in, const int* in_sizes, int n_in,
                              void* d_out, int out_size, void* d_ws, size_t ws_size,
                              hipStream_t stream)
{
  (void)in_sizes; (void)n_in; (void)out_size;
  const float* x    = (const float*)d_in[0];
  const int* eidx   = (const int*)d_in[1];
  const float* ea   = (const float*)d_in[2];
  const float* Wl1  = (const float*)d_in[3];
  const float* bl1  = (const float*)d_in[4];
  const float* Wr1  = (const float*)d_in[5];
  const float* br1  = (const float*)d_in[6];
  const float* We1  = (const float*)d_in[7];
  const float* att1 = (const float*)d_in[8];
  const float* bias1= (const float*)d_in[9];
  const float* Wl2  = (const float*)d_in[10];
  const float* bl2  = (const float*)d_in[11];
  const float* Wr2  = (const float*)d_in[12];
  const float* br2  = (const float*)d_in[13];
  const float* We2  = (const float*)d_in[14];
  const float* att2 = (const float*)d_in[15];
  const float* bias2= (const float*)d_in[16];
  const float* Wh1  = (const float*)d_in[17];
  const float* bh1  = (const float*)d_in[18];
  const float* Wh2  = (const float*)d_in[19];
  const float* bh2  = (const float*)d_in[20];
  const int* srcs = eidx;
  const int* dsts = eidx + N_EDGES;
  float* out = (float*)d_out;

  const size_t szBig = (size_t)N_NODES * HC1 * sizeof(float);
  auto aln = [](size_t b) { return (b + 511) & ~(size_t)511; };
  size_t smallSz = aln((size_t)N_NODES * 4) * 2 + aln((size_t)(N_NODES + 1) * 4)
                 + aln((size_t)N_EDGES * 4);
  size_t needF = aln(szBig) * 3 + smallSz + 4096;
  bool useBF = ws_size < needF;

  char* p = (char*)d_ws;
  auto alloc = [&](size_t bytes) { char* q = p; p += (bytes + 511) & ~(size_t)511; return q; };
  float* xl1 = (float*)alloc(szBig);
  float* xr1 = (float*)alloc(szBig);          // reused for xl2/xr2 after fused1
  void*  h1  = (void*)alloc(useBF ? szBig / 2 : szBig);
  int* deg    = (int*)alloc((size_t)N_NODES * 4);
  int* offs   = (int*)alloc((size_t)(N_NODES + 1) * 4);
  int* cursor = (int*)alloc((size_t)N_NODES * 4);
  int* csr    = (int*)alloc((size_t)N_EDGES * 4);
  float* xl2 = xr1;
  float* xr2 = xr1 + (size_t)N_NODES * HID;
  float* h2  = xl1;                            // xl1 region dead after fused1

  hipMemsetAsync(deg, 0, (size_t)N_NODES * 4, stream);
  hipLaunchKernelGGL(deg_count_kernel, dim3((N_EDGES + 255) / 256), dim3(256), 0, stream, dsts, deg);
  hipLaunchKernelGGL(scan_kernel, dim3(1), dim3(1024), 0, stream, deg, offs, cursor);
  hipLaunchKernelGGL(scatter_kernel, dim3((N_EDGES + 255) / 256), dim3(256), 0, stream, dsts, cursor, csr);
  hipLaunchKernelGGL(linear1_kernel, dim3(N_NODES / 16), dim3(256), 0, stream,
                     x, Wl1, bl1, Wr1, br1, xl1, xr1);
  // fused1: grid = (N/8 node-groups) x 2 halves
  if (useBF)
    hipLaunchKernelGGL((fused1_kernel<true>), dim3((N_NODES / 8) * 2), dim3(512), 0, stream,
                       ea, srcs, We1, att1, xl1, xr1, bias1, offs, csr, h1);
  else
    hipLaunchKernelGGL((fused1_kernel<false>), dim3((N_NODES / 8) * 2), dim3(512), 0, stream,
                       ea, srcs, We1, att1, xl1, xr1, bias1, offs, csr, h1);
  if (useBF)
    hipLaunchKernelGGL((linear2_kernel<true>), dim3(N_NODES / 16), dim3(256), 0, stream,
                       h1, Wl2, bl2, Wr2, br2, xl2, xr2);
  else
    hipLaunchKernelGGL((linear2_kernel<false>), dim3(N_NODES / 16), dim3(256), 0, stream,
                       h1, Wl2, bl2, Wr2, br2, xl2, xr2);
  hipLaunchKernelGGL(fused2_kernel, dim3(N_NODES / 8), dim3(512), 0, stream,
                     ea, srcs, We2, att2, xl2, xr2, bias2, offs, csr, h2);
  hipLaunchKernelGGL(head_kernel, dim3(N_NODES / 16), dim3(256), 0, stream,
                     h2, Wh1, bh1, Wh2, bh2, out);
}

// Round 13
// 556.708 us; speedup vs baseline: 1.1771x; 1.0874x over previous
//
#include <hip/hip_runtime.h>
#include <hip/hip_bf16.h>
#include <math.h>

#define N_NODES 20000
#define N_EDGES 320000
#define NODE_DIM 64
#define EDGE_DIM 32
#define HID 128
#define HEADS 4
#define HC1 512   // HEADS*HID
#define NEG_SLOPE 0.2f

typedef __attribute__((ext_vector_type(8))) short bf16x8;
typedef __attribute__((ext_vector_type(4))) float f32x4;

__device__ __forceinline__ unsigned short f2b(float f) {
  unsigned u = __float_as_uint(f);
  unsigned r = (u + 0x7fffu + ((u >> 16) & 1u)) >> 16;
  return (unsigned short)r;
}
__device__ __forceinline__ float b2f(unsigned short b) {
  return __uint_as_float(((unsigned)b) << 16);
}

// ---------------- CSR build ----------------
__global__ void deg_count_kernel(const int* __restrict__ dsts, int* __restrict__ deg) {
  int e = blockIdx.x * blockDim.x + threadIdx.x;
  if (e < N_EDGES) atomicAdd(&deg[dsts[e]], 1);
}

__global__ __launch_bounds__(1024) void scan_kernel(
    const int* __restrict__ deg, int* __restrict__ offs, int* __restrict__ cursor)
{
  __shared__ int part[1024];
  int t = threadIdx.x;
  const int C = 20;                 // 1024*20 = 20480 >= N_NODES
  int base = t * C;
  int loc[C]; int s = 0;
  #pragma unroll
  for (int i = 0; i < C; i++) { loc[i] = s; int idx = base + i; s += (idx < N_NODES) ? deg[idx] : 0; }
  part[t] = s;
  __syncthreads();
  for (int off = 1; off < 1024; off <<= 1) {
    int v = (t >= off) ? part[t - off] : 0;
    __syncthreads();
    part[t] += v;
    __syncthreads();
  }
  int pbase = (t > 0) ? part[t - 1] : 0;
  #pragma unroll
  for (int i = 0; i < C; i++) {
    int idx = base + i;
    if (idx < N_NODES) { int o = pbase + loc[i]; offs[idx] = o; cursor[idx] = o; }
  }
  if (t == 1023) offs[N_NODES] = part[1023];
}

__global__ void scatter_kernel(const int* __restrict__ dsts, int* __restrict__ cursor,
                               int* __restrict__ csr) {
  int e = blockIdx.x * blockDim.x + threadIdx.x;
  if (e >= N_EDGES) return;
  int pos = atomicAdd(&cursor[dsts[e]], 1);
  csr[pos] = e;
}

// ---------------- linear1 ----------------
__global__ __launch_bounds__(256) void linear1_kernel(
    const float* __restrict__ x, const float* __restrict__ Wl,
    const float* __restrict__ bl, const float* __restrict__ Wr,
    const float* __restrict__ br, float* __restrict__ xl, float* __restrict__ xr)
{
  __shared__ float xsT[NODE_DIM][16];
  int n0 = blockIdx.x * 16;
  int t = threadIdx.x;
  {
    int flat = t * 4;
    int i = flat >> 6, k = flat & 63;
    float4 v = *(const float4*)&x[(size_t)(n0 + i) * NODE_DIM + k];
    xsT[k + 0][i] = v.x; xsT[k + 1][i] = v.y; xsT[k + 2][i] = v.z; xsT[k + 3][i] = v.w;
  }
  __syncthreads();
  for (int m = 0; m < 2; m++) {
    const float* W  = m ? Wr : Wl;
    const float* bb = m ? br : bl;
    float* out = m ? xr : xl;
    for (int jh = 0; jh < 2; jh++) {
      int j = t + jh * 256;
      float acc[16];
      #pragma unroll
      for (int i = 0; i < 16; i++) acc[i] = 0.f;
      for (int k = 0; k < NODE_DIM; k++) {
        float w = W[k * HC1 + j];
        float xv[16];
        *(float4*)&xv[0]  = *(const float4*)&xsT[k][0];
        *(float4*)&xv[4]  = *(const float4*)&xsT[k][4];
        *(float4*)&xv[8]  = *(const float4*)&xsT[k][8];
        *(float4*)&xv[12] = *(const float4*)&xsT[k][12];
        #pragma unroll
        for (int i = 0; i < 16; i++) acc[i] = fmaf(xv[i], w, acc[i]);
      }
      float bj = bb[j];
      #pragma unroll
      for (int i = 0; i < 16; i++) out[(size_t)(n0 + i) * HC1 + j] = acc[i] + bj;
    }
  }
}

// ---------------- fused layer 1 (R11 MFMA orientation; pads 42/272; no perm) ----------------
// block = 512 threads = 8 waves = 8 nodes x ONE half (half = blockIdx&1).
// ee = ea@We via mfma_f32_16x16x32_bf16: A = edge tile (rows 0-3 real) from LDS,
// B = WtT tiles from LDS per chunk. D: row=(lane>>4)*4+reg = edge, col=lane&15 = ch.
template<bool H1BF>
__global__ __launch_bounds__(512, 2) void fused1_kernel(
    const float* __restrict__ ea, const int* __restrict__ srcs,
    const float* __restrict__ We, const float* __restrict__ att,
    const float* __restrict__ xl, const float* __restrict__ xr,
    const float* __restrict__ bias, const int* __restrict__ offs,
    const int* __restrict__ csr, void* __restrict__ h1out)
{
  __shared__ short WtT[256 * 42];        // 21KB: half's We, transposed [ch][k], bf16, rows padded to 42
  __shared__ short easb[8][16 * 42];     // 10.5KB: per-wave A tile (16 rows x 42), rows 0-3 real
  __shared__ float ee_s[8][4][272];      // 34.8KB: per-wave ee result, 4 edges x 256ch (+pad)
  int t = threadIdx.x;
  int half = blockIdx.x & 1;
  for (int i = t; i < EDGE_DIM * 256; i += 512) {
    int k = i >> 8, c = i & 255;
    WtT[c * 42 + k] = (short)f2b(We[(size_t)k * HC1 + half * 256 + c]);
  }
  __syncthreads();
  int wave = t >> 6, lane = t & 63;
  int l15 = lane & 15, l16 = lane >> 4;
  int n = (blockIdx.x >> 1) * 8 + wave;   // 2500 groups * 8 = 20000 exact
  int Cl = lane * 4;                 // channel within the half
  int C = half * 256 + Cl;           // global channel
  float at4[4], xr4[4];
  *(float4*)at4 = *(const float4*)&att[C];
  *(float4*)xr4 = *(const float4*)&xr[(size_t)n * HC1 + C];
  float o4[4] = {0.f,0.f,0.f,0.f};
  float mx = 8.0f, dn = 0.f;
  int beg = offs[n], end = offs[n + 1];
  int ev = 0, sv = 0;
  if (lane < 4 && beg + lane < end) { ev = csr[beg + lane]; sv = srcs[ev]; }
  for (int i0 = beg; i0 < end; i0 += 4) {
    int nv = end - i0; if (nv > 4) nv = 4;
    int sarr[4];
    #pragma unroll
    for (int j = 0; j < 4; j++) sarr[j] = __shfl(sv, j);
    // issue xl gathers FIRST (latency hides under staging + MFMA below)
    float xv0[4], xv1[4], xv2[4], xv3[4];
    #pragma unroll
    for (int c = 0; c < 4; c++) { xv0[c] = 0.f; xv1[c] = 0.f; xv2[c] = 0.f; xv3[c] = 0.f; }
    if (0 < nv) *(float4*)xv0 = *(const float4*)&xl[(size_t)sarr[0] * HC1 + C];
    if (1 < nv) *(float4*)xv1 = *(const float4*)&xl[(size_t)sarr[1] * HC1 + C];
    if (2 < nv) *(float4*)xv2 = *(const float4*)&xl[(size_t)sarr[2] * HC1 + C];
    if (3 < nv) *(float4*)xv3 = *(const float4*)&xl[(size_t)sarr[3] * HC1 + C];
    // stage the chunk's 4 ea rows as bf16 (lanes 0-15: edge=lane>>2, quarter q=lane&3)
    {
      int me = __shfl(ev, (lane >> 2) & 3);
      if (lane < 16) {
        int q = lane & 3;
        float4 u0 = *(const float4*)&ea[(size_t)me * EDGE_DIM + q * 8];
        float4 u1 = *(const float4*)&ea[(size_t)me * EDGE_DIM + q * 8 + 4];
        short* dst = &easb[wave][(lane >> 2) * 42 + q * 8];
        dst[0] = (short)f2b(u0.x); dst[1] = (short)f2b(u0.y);
        dst[2] = (short)f2b(u0.z); dst[3] = (short)f2b(u0.w);
        dst[4] = (short)f2b(u1.x); dst[5] = (short)f2b(u1.y);
        dst[6] = (short)f2b(u1.z); dst[7] = (short)f2b(u1.w);
      }
    }
    // prefetch next chunk's indices
    if (lane < 4 && i0 + 4 + lane < end) { ev = csr[i0 + 4 + lane]; sv = srcs[ev]; }
    // MFMA: 16 tiles of 16 ch, K=32 in one instruction each
    bf16x8 afrag = *(bf16x8*)&easb[wave][l15 * 42 + l16 * 8];
    #pragma unroll 4
    for (int tt = 0; tt < 16; tt++) {
      bf16x8 bfrag = *(bf16x8*)&WtT[(tt * 16 + l15) * 42 + l16 * 8];
      f32x4 cz = {0.f, 0.f, 0.f, 0.f};
      f32x4 cv = __builtin_amdgcn_mfma_f32_16x16x32_bf16(afrag, bfrag, cz, 0, 0, 0);
      if (lane < 16) {
        #pragma unroll
        for (int r = 0; r < 4; r++) ee_s[wave][r][tt * 16 + lane] = cv[r];
      }
    }
    // tail: read a4 from ee_s; logits; softmax; accumulate
    float a40[4], a41[4], a42[4], a43[4];
    *(float4*)a40 = *(const float4*)&ee_s[wave][0][Cl];
    *(float4*)a41 = *(const float4*)&ee_s[wave][1][Cl];
    *(float4*)a42 = *(const float4*)&ee_s[wave][2][Cl];
    *(float4*)a43 = *(const float4*)&ee_s[wave][3][Cl];
    float pl[4];
    #pragma unroll
    for (int j = 0; j < 4; j++) {
      const float* aj  = (j == 0) ? a40 : (j == 1) ? a41 : (j == 2) ? a42 : a43;
      const float* xvj = (j == 0) ? xv0 : (j == 1) ? xv1 : (j == 2) ? xv2 : xv3;
      float s = 0.f;
      #pragma unroll
      for (int c = 0; c < 4; c++) {
        float z = aj[c] + xvj[c] + xr4[c];
        float zm = z > 0.f ? z : NEG_SLOPE * z;
        s = fmaf(zm, at4[c], s);
      }
      #pragma unroll
      for (int o = 1; o <= 16; o <<= 1) s += __shfl_xor(s, o);
      pl[j] = (j < nv) ? s : -3.0e38f;
    }
    float cm = fmaxf(fmaxf(pl[0], pl[1]), fmaxf(pl[2], pl[3]));
    float mn = fmaxf(mx, cm);
    if (__any(mn > mx + 8.f)) {
      float fs = __expf(mx - mn);
      dn *= fs;
      #pragma unroll
      for (int c = 0; c < 4; c++) o4[c] *= fs;
      mx = mn;
    }
    float p[4];
    #pragma unroll
    for (int j = 0; j < 4; j++) p[j] = __expf(pl[j] - mx);
    dn += (p[0] + p[1]) + (p[2] + p[3]);
    #pragma unroll
    for (int c = 0; c < 4; c++) {
      o4[c] += (p[0] * xv0[c] + p[1] * xv1[c]) + (p[2] * xv2[c] + p[3] * xv3[c]);
    }
  }
  float iv = dn > 0.f ? 1.f / dn : 0.f;
  float r[4];
  #pragma unroll
  for (int c = 0; c < 4; c++) {
    float v = o4[c] * iv + bias[C + c];
    r[c] = v > 0.f ? v : 0.f;            // relu after conv1
  }
  if (H1BF) {
    unsigned short* hb = (unsigned short*)h1out;
    ushort4 u;
    u.x = f2b(r[0]); u.y = f2b(r[1]); u.z = f2b(r[2]); u.w = f2b(r[3]);
    *(ushort4*)&hb[(size_t)n * HC1 + C] = u;
  } else {
    float* hf = (float*)h1out;
    *(float4*)&hf[(size_t)n * HC1 + C] = *(float4*)r;
  }
}

// ---------------- linear2 ----------------
template<bool INBF>
__global__ __launch_bounds__(256) void linear2_kernel(
    const void* __restrict__ hin_, const float* __restrict__ Wl,
    const float* __restrict__ bl, const float* __restrict__ Wr,
    const float* __restrict__ br, float* __restrict__ xl, float* __restrict__ xr)
{
  __shared__ float xsT[HC1][16];   // 32KB
  int n0 = blockIdx.x * 16;
  int t = threadIdx.x;
  for (int r = 0; r < 8; r++) {
    int flat = (t + r * 256) * 4;
    int i = flat >> 9, k = flat & 511;
    float4 v;
    if (INBF) {
      const unsigned short* hb = (const unsigned short*)hin_;
      ushort4 u = *(const ushort4*)&hb[(size_t)(n0 + i) * HC1 + k];
      v.x = b2f(u.x); v.y = b2f(u.y); v.z = b2f(u.z); v.w = b2f(u.w);
    } else {
      const float* hf = (const float*)hin_;
      v = *(const float4*)&hf[(size_t)(n0 + i) * HC1 + k];
    }
    xsT[k + 0][i] = v.x; xsT[k + 1][i] = v.y; xsT[k + 2][i] = v.z; xsT[k + 3][i] = v.w;
  }
  __syncthreads();
  int m = t >> 7, j = t & 127;
  const float* W = m ? Wr : Wl;
  float bj = (m ? br : bl)[j];
  float* out = m ? xr : xl;
  float acc[16];
  #pragma unroll
  for (int i = 0; i < 16; i++) acc[i] = 0.f;
  for (int k = 0; k < HC1; k++) {
    float w = W[k * HID + j];
    float xv[16];
    *(float4*)&xv[0]  = *(const float4*)&xsT[k][0];
    *(float4*)&xv[4]  = *(const float4*)&xsT[k][4];
    *(float4*)&xv[8]  = *(const float4*)&xsT[k][8];
    *(float4*)&xv[12] = *(const float4*)&xsT[k][12];
    #pragma unroll
    for (int i = 0; i < 16; i++) acc[i] = fmaf(xv[i], w, acc[i]);
  }
  #pragma unroll
  for (int i = 0; i < 16; i++) out[(size_t)(n0 + i) * HID + j] = acc[i] + bj;
}

// ---------------- fused layer 2 (MFMA port; 8-edge chunks) ----------------
// block = 512 threads = 8 waves = 8 nodes. lane owns channels {2*lane, 2*lane+1}.
// ee = ea@We2 via MFMA: A = edge tile (rows 0-7 real), B = W2tT tiles (8 of them).
// D: row=(lane>>4)*4+reg = edge, col=lane&15 = ch-in-tile; lanes<32 scatter rows 0-7.
__global__ __launch_bounds__(512, 2) void fused2_kernel(
    const float* __restrict__ ea, const int* __restrict__ srcs,
    const float* __restrict__ We, const float* __restrict__ att,
    const float* __restrict__ xl, const float* __restrict__ xr,
    const float* __restrict__ bias, const int* __restrict__ offs,
    const int* __restrict__ csr, float* __restrict__ h2out)
{
  __shared__ short W2tT[HID * 42];       // 10.5KB: We2 transposed [ch][k], bf16
  __shared__ short easb2[8][16 * 42];    // 10.5KB: per-wave A tile, rows 0-7 real
  __shared__ float ee2[8][8][132];       // 33.8KB: per-wave ee, 8 edges x 128ch (+pad)
  int t = threadIdx.x;
  for (int i = t; i < EDGE_DIM * HID; i += 512) {
    int k = i >> 7, c = i & 127;
    W2tT[c * 42 + k] = (short)f2b(We[(size_t)k * HID + c]);
  }
  __syncthreads();
  int wave = t >> 6, lane = t & 63;
  int l15 = lane & 15, l16 = lane >> 4;
  int n = blockIdx.x * 8 + wave;
  int c = lane * 2;
  float2 atv = *(const float2*)&att[c];
  float2 xrv = *(const float2*)&xr[(size_t)n * HID + c];
  float oa = 0.f, ob = 0.f;
  float m = 8.0f, d = 0.f;
  int beg = offs[n], end = offs[n + 1];
  int ev = 0, sv = 0;
  if (lane < 8 && beg + lane < end) { ev = csr[beg + lane]; sv = srcs[ev]; }
  for (int i0 = beg; i0 < end; i0 += 8) {
    int nv = end - i0; if (nv > 8) nv = 8;
    int sarr[8];
    #pragma unroll
    for (int j = 0; j < 8; j++) sarr[j] = __shfl(sv, j);
    // issue xl gathers first (float2, coalesced across lanes)
    float2 xv[8];
    #pragma unroll
    for (int j = 0; j < 8; j++) {
      if (j < nv) xv[j] = *(const float2*)&xl[(size_t)sarr[j] * HID + c];
      else { xv[j].x = 0.f; xv[j].y = 0.f; }
    }
    // stage 8 ea rows as bf16 (lanes 0-31: edge=lane>>2, quarter q=lane&3)
    {
      int me = __shfl(ev, lane >> 2);
      if (lane < 32) {
        int q = lane & 3;
        float4 u0 = *(const float4*)&ea[(size_t)me * EDGE_DIM + q * 8];
        float4 u1 = *(const float4*)&ea[(size_t)me * EDGE_DIM + q * 8 + 4];
        short* dst = &easb2[wave][(lane >> 2) * 42 + q * 8];
        dst[0] = (short)f2b(u0.x); dst[1] = (short)f2b(u0.y);
        dst[2] = (short)f2b(u0.z); dst[3] = (short)f2b(u0.w);
        dst[4] = (short)f2b(u1.x); dst[5] = (short)f2b(u1.y);
        dst[6] = (short)f2b(u1.z); dst[7] = (short)f2b(u1.w);
      }
    }
    // prefetch next chunk's indices
    if (lane < 8 && i0 + 8 + lane < end) { ev = csr[i0 + 8 + lane]; sv = srcs[ev]; }
    // MFMA: 8 tiles of 16 ch, K=32
    bf16x8 afrag = *(bf16x8*)&easb2[wave][l15 * 42 + l16 * 8];
    #pragma unroll 4
    for (int tt = 0; tt < 8; tt++) {
      bf16x8 bfrag = *(bf16x8*)&W2tT[(tt * 16 + l15) * 42 + l16 * 8];
      f32x4 cz = {0.f, 0.f, 0.f, 0.f};
      f32x4 cv = __builtin_amdgcn_mfma_f32_16x16x32_bf16(afrag, bfrag, cz, 0, 0, 0);
      if (lane < 32) {
        int erow = (lane >> 4) * 4;           // 0 or 4
        #pragma unroll
        for (int r = 0; r < 4; r++) ee2[wave][erow + r][tt * 16 + l15] = cv[r];
      }
    }
    // tail: logits from ee2 + xl + xr; 8 independent 64-lane butterflies
    float pl[8];
    #pragma unroll
    for (int j = 0; j < 8; j++) {
      float2 av = *(const float2*)&ee2[wave][j][c];
      float za = av.x + xv[j].x + xrv.x;
      float zb = av.y + xv[j].y + xrv.y;
      za = za > 0.f ? za : NEG_SLOPE * za;
      zb = zb > 0.f ? zb : NEG_SLOPE * zb;
      float s = za * atv.x + zb * atv.y;
      #pragma unroll
      for (int o = 1; o < 64; o <<= 1) s += __shfl_xor(s, o);
      pl[j] = (j < nv) ? s : -3.0e38f;
    }
    float cm = fmaxf(fmaxf(fmaxf(pl[0], pl[1]), fmaxf(pl[2], pl[3])),
                     fmaxf(fmaxf(pl[4], pl[5]), fmaxf(pl[6], pl[7])));
    float mn = fmaxf(m, cm);
    if (__any(mn > m + 8.f)) {
      float fs = __expf(m - mn);
      d *= fs; oa *= fs; ob *= fs;
      m = mn;
    }
    float p[8];
    #pragma unroll
    for (int j = 0; j < 8; j++) p[j] = __expf(pl[j] - m);
    d += ((p[0] + p[1]) + (p[2] + p[3])) + ((p[4] + p[5]) + (p[6] + p[7]));
    #pragma unroll
    for (int j = 0; j < 8; j++) {
      oa = fmaf(p[j], xv[j].x, oa);
      ob = fmaf(p[j], xv[j].y, ob);
    }
  }
  float invd = d > 0.f ? 1.f / d : 0.f;
  float2 o2 = make_float2(oa * invd + bias[c], ob * invd + bias[c + 1]); // no relu after conv2
  *(float2*)&h2out[(size_t)n * HID + c] = o2;
}

// ---------------- MLP head ----------------
__global__ __launch_bounds__(256) void head_kernel(
    const float* __restrict__ h2, const float* __restrict__ Wh1,
    const float* __restrict__ bh1, const float* __restrict__ Wh2,
    const float* __restrict__ bh2, float* __restrict__ out)
{
  __shared__ float hs[16][HID];   // 8KB
  __shared__ float ts[16][64];    // 4KB
  int n0 = blockIdx.x * 16;
  int t = threadIdx.x;
  for (int r = 0; r < 2; r++) {
    int flat = (t + r * 256) * 4; // 2048 floats
    int i = flat >> 7, k = flat & 127;
    *(float4*)&hs[i][k] = *(const float4*)&h2[(size_t)(n0 + i) * HID + k];
  }
  __syncthreads();
  int j = t & 63, g = t >> 6;
  float acc[4];
  #pragma unroll
  for (int q = 0; q < 4; q++) acc[q] = 0.f;
  for (int k = 0; k < HID; k++) {
    float w = Wh1[k * 64 + j];
    #pragma unroll
    for (int q = 0; q < 4; q++) acc[q] = fmaf(hs[g + 4 * q][k], w, acc[q]);
  }
  float bj = bh1[j];
  #pragma unroll
  for (int q = 0; q < 4; q++) {
    float v = acc[q] + bj;
    ts[g + 4 * q][j] = v > 0.f ? v : 0.f;
  }
  __syncthreads();
  if (t < 32) {
    int nl = t >> 1, k = t & 1;
    float acc2 = bh2[k];
    for (int jj = 0; jj < 64; jj++) acc2 = fmaf(ts[nl][jj], Wh2[jj * 2 + k], acc2);
    out[(size_t)(n0 + nl) * 2 + k] = acc2;
  }
}

extern "C" void kernel_launch(void* const* d_in, const int* in_sizes, int n_in,
                              void* d_out, int out_size, void* d_ws, size_t ws_size,
                              hipStream_t stream)
{
  (void)in_sizes; (void)n_in; (void)out_size;
  const float* x    = (const float*)d_in[0];
  const int* eidx   = (const int*)d_in[1];
  const float* ea   = (const float*)d_in[2];
  const float* Wl1  = (const float*)d_in[3];
  const float* bl1  = (const float*)d_in[4];
  const float* Wr1  = (const float*)d_in[5];
  const float* br1  = (const float*)d_in[6];
  const float* We1  = (const float*)d_in[7];
  const float* att1 = (const float*)d_in[8];
  const float* bias1= (const float*)d_in[9];
  const float* Wl2  = (const float*)d_in[10];
  const float* bl2  = (const float*)d_in[11];
  const float* Wr2  = (const float*)d_in[12];
  const float* br2  = (const float*)d_in[13];
  const float* We2  = (const float*)d_in[14];
  const float* att2 = (const float*)d_in[15];
  const float* bias2= (const float*)d_in[16];
  const float* Wh1  = (const float*)d_in[17];
  const float* bh1  = (const float*)d_in[18];
  const float* Wh2  = (const float*)d_in[19];
  const float* bh2  = (const float*)d_in[20];
  const int* srcs = eidx;
  const int* dsts = eidx + N_EDGES;
  float* out = (float*)d_out;

  const size_t szBig = (size_t)N_NODES * HC1 * sizeof(float);
  auto aln = [](size_t b) { return (b + 511) & ~(size_t)511; };
  size_t smallSz = aln((size_t)N_NODES * 4) * 2 + aln((size_t)(N_NODES + 1) * 4)
                 + aln((size_t)N_EDGES * 4);
  size_t needF = aln(szBig) * 3 + smallSz + 4096;
  bool useBF = ws_size < needF;

  char* p = (char*)d_ws;
  auto alloc = [&](size_t bytes) { char* q = p; p += (bytes + 511) & ~(size_t)511; return q; };
  float* xl1 = (float*)alloc(szBig);
  float* xr1 = (float*)alloc(szBig);          // reused for xl2/xr2 after fused1
  void*  h1  = (void*)alloc(useBF ? szBig / 2 : szBig);
  int* deg    = (int*)alloc((size_t)N_NODES * 4);
  int* offs   = (int*)alloc((size_t)(N_NODES + 1) * 4);
  int* cursor = (int*)alloc((size_t)N_NODES * 4);
  int* csr    = (int*)alloc((size_t)N_EDGES * 4);
  float* xl2 = xr1;
  float* xr2 = xr1 + (size_t)N_NODES * HID;
  float* h2  = xl1;                            // xl1 region dead after fused1

  hipMemsetAsync(deg, 0, (size_t)N_NODES * 4, stream);
  hipLaunchKernelGGL(deg_count_kernel, dim3((N_EDGES + 255) / 256), dim3(256), 0, stream, dsts, deg);
  hipLaunchKernelGGL(scan_kernel, dim3(1), dim3(1024), 0, stream, deg, offs, cursor);
  hipLaunchKernelGGL(scatter_kernel, dim3((N_EDGES + 255) / 256), dim3(256), 0, stream, dsts, cursor, csr);
  hipLaunchKernelGGL(linear1_kernel, dim3(N_NODES / 16), dim3(256), 0, stream,
                     x, Wl1, bl1, Wr1, br1, xl1, xr1);
  // fused1: grid = (N/8 node-groups) x 2 halves
  if (useBF)
    hipLaunchKernelGGL((fused1_kernel<true>), dim3((N_NODES / 8) * 2), dim3(512), 0, stream,
                       ea, srcs, We1, att1, xl1, xr1, bias1, offs, csr, h1);
  else
    hipLaunchKernelGGL((fused1_kernel<false>), dim3((N_NODES / 8) * 2), dim3(512), 0, stream,
                       ea, srcs, We1, att1, xl1, xr1, bias1, offs, csr, h1);
  if (useBF)
    hipLaunchKernelGGL((linear2_kernel<true>), dim3(N_NODES / 16), dim3(256), 0, stream,
                       h1, Wl2, bl2, Wr2, br2, xl2, xr2);
  else
    hipLaunchKernelGGL((linear2_kernel<false>), dim3(N_NODES / 16), dim3(256), 0, stream,
                       h1, Wl2, bl2, Wr2, br2, xl2, xr2);
  hipLaunchKernelGGL(fused2_kernel, dim3(N_NODES / 8), dim3(512), 0, stream,
                     ea, srcs, We2, att2, xl2, xr2, bias2, offs, csr, h2);
  hipLaunchKernelGGL(head_kernel, dim3(N_NODES / 16), dim3(256), 0, stream,
                     h2, Wh1, bh1, Wh2, bh2, out);
}

// Round 14
// 479.517 us; speedup vs baseline: 1.3666x; 1.1610x over previous
//
#include <hip/hip_runtime.h>
#include <hip/hip_bf16.h>
#include <math.h>

#define N_NODES 20000
#define N_EDGES 320000
#define NODE_DIM 64
#define EDGE_DIM 32
#define HID 128
#define HEADS 4
#define HC1 512   // HEADS*HID
#define NEG_SLOPE 0.2f

typedef __attribute__((ext_vector_type(8))) short bf16x8;
typedef __attribute__((ext_vector_type(4))) float f32x4;

__device__ __forceinline__ unsigned short f2b(float f) {
  unsigned u = __float_as_uint(f);
  unsigned r = (u + 0x7fffu + ((u >> 16) & 1u)) >> 16;
  return (unsigned short)r;
}
__device__ __forceinline__ float b2f(unsigned short b) {
  return __uint_as_float(((unsigned)b) << 16);
}

// ---------------- CSR build ----------------
__global__ void deg_count_kernel(const int* __restrict__ dsts, int* __restrict__ deg) {
  int e = blockIdx.x * blockDim.x + threadIdx.x;
  if (e < N_EDGES) atomicAdd(&deg[dsts[e]], 1);
}

__global__ __launch_bounds__(1024) void scan_kernel(
    const int* __restrict__ deg, int* __restrict__ offs, int* __restrict__ cursor)
{
  __shared__ int part[1024];
  int t = threadIdx.x;
  const int C = 20;                 // 1024*20 = 20480 >= N_NODES
  int base = t * C;
  int loc[C]; int s = 0;
  #pragma unroll
  for (int i = 0; i < C; i++) { loc[i] = s; int idx = base + i; s += (idx < N_NODES) ? deg[idx] : 0; }
  part[t] = s;
  __syncthreads();
  for (int off = 1; off < 1024; off <<= 1) {
    int v = (t >= off) ? part[t - off] : 0;
    __syncthreads();
    part[t] += v;
    __syncthreads();
  }
  int pbase = (t > 0) ? part[t - 1] : 0;
  #pragma unroll
  for (int i = 0; i < C; i++) {
    int idx = base + i;
    if (idx < N_NODES) { int o = pbase + loc[i]; offs[idx] = o; cursor[idx] = o; }
  }
  if (t == 1023) offs[N_NODES] = part[1023];
}

__global__ void scatter_kernel(const int* __restrict__ dsts, int* __restrict__ cursor,
                               int* __restrict__ csr) {
  int e = blockIdx.x * blockDim.x + threadIdx.x;
  if (e >= N_EDGES) return;
  int pos = atomicAdd(&cursor[dsts[e]], 1);
  csr[pos] = e;
}

// ---------------- linear1 ----------------
__global__ __launch_bounds__(256) void linear1_kernel(
    const float* __restrict__ x, const float* __restrict__ Wl,
    const float* __restrict__ bl, const float* __restrict__ Wr,
    const float* __restrict__ br, float* __restrict__ xl, float* __restrict__ xr)
{
  __shared__ float xsT[NODE_DIM][16];
  int n0 = blockIdx.x * 16;
  int t = threadIdx.x;
  {
    int flat = t * 4;
    int i = flat >> 6, k = flat & 63;
    float4 v = *(const float4*)&x[(size_t)(n0 + i) * NODE_DIM + k];
    xsT[k + 0][i] = v.x; xsT[k + 1][i] = v.y; xsT[k + 2][i] = v.z; xsT[k + 3][i] = v.w;
  }
  __syncthreads();
  for (int m = 0; m < 2; m++) {
    const float* W  = m ? Wr : Wl;
    const float* bb = m ? br : bl;
    float* out = m ? xr : xl;
    for (int jh = 0; jh < 2; jh++) {
      int j = t + jh * 256;
      float acc[16];
      #pragma unroll
      for (int i = 0; i < 16; i++) acc[i] = 0.f;
      for (int k = 0; k < NODE_DIM; k++) {
        float w = W[k * HC1 + j];
        float xv[16];
        *(float4*)&xv[0]  = *(const float4*)&xsT[k][0];
        *(float4*)&xv[4]  = *(const float4*)&xsT[k][4];
        *(float4*)&xv[8]  = *(const float4*)&xsT[k][8];
        *(float4*)&xv[12] = *(const float4*)&xsT[k][12];
        #pragma unroll
        for (int i = 0; i < 16; i++) acc[i] = fmaf(xv[i], w, acc[i]);
      }
      float bj = bb[j];
      #pragma unroll
      for (int i = 0; i < 16; i++) out[(size_t)(n0 + i) * HC1 + j] = acc[i] + bj;
    }
  }
}

// ---------------- fused layer 1 (MFMA, 8-edge chunks, bf16 ee roundtrip) ----------------
// block = 512 threads = 8 waves = 8 nodes x ONE half (half = blockIdx&1).
// ee = ea@We via mfma_f32_16x16x32_bf16: A = WtT tiles (M=channels), B = edge
// tile (N=edges, rows 0-7 real). D[m=ch][n=edge]: lane(l15=edge, l16) holds 4
// consecutive channels tt*16+l16*4..+3 -> one 8B bf16x4 store per lane (l15<8).
template<bool H1BF>
__global__ __launch_bounds__(512, 2) void fused1_kernel(
    const float* __restrict__ ea, const int* __restrict__ srcs,
    const float* __restrict__ We, const float* __restrict__ att,
    const float* __restrict__ xl, const float* __restrict__ xr,
    const float* __restrict__ bias, const int* __restrict__ offs,
    const int* __restrict__ csr, void* __restrict__ h1out)
{
  __shared__ short WtT[256 * 40];        // 20KB: half's We transposed [ch][k], bf16, stride 40
  __shared__ short easb[8][16 * 40];     // 10KB: per-wave B tile, rows 0-7 real
  __shared__ short ee_b[8][8][264];      // 33KB: per-wave ee (bf16), 8 edges x 256ch (+pad)
  int t = threadIdx.x;
  int half = blockIdx.x & 1;
  for (int i = t; i < EDGE_DIM * 256; i += 512) {
    int k = i >> 8, c = i & 255;
    WtT[c * 40 + k] = (short)f2b(We[(size_t)k * HC1 + half * 256 + c]);
  }
  __syncthreads();
  int wave = t >> 6, lane = t & 63;
  int l15 = lane & 15, l16 = lane >> 4;
  int n = (blockIdx.x >> 1) * 8 + wave;   // 2500 groups * 8 = 20000 exact
  int Cl = lane * 4;                 // channel within the half
  int C = half * 256 + Cl;           // global channel
  float at4[4], xr4[4];
  *(float4*)at4 = *(const float4*)&att[C];
  *(float4*)xr4 = *(const float4*)&xr[(size_t)n * HC1 + C];
  float o4[4] = {0.f,0.f,0.f,0.f};
  float mx = 8.0f, dn = 0.f;
  int beg = offs[n], end = offs[n + 1];
  int ev = 0, sv = 0;
  if (lane < 8 && beg + lane < end) { ev = csr[beg + lane]; sv = srcs[ev]; }
  for (int i0 = beg; i0 < end; i0 += 8) {
    int nv = end - i0; if (nv > 8) nv = 8;
    int sarr[8];
    #pragma unroll
    for (int j = 0; j < 8; j++) sarr[j] = __shfl(sv, j);
    // issue xl gathers FIRST (latency hides under staging + MFMA below)
    float xv[8][4];
    #pragma unroll
    for (int j = 0; j < 8; j++) {
      if (j < nv) *(float4*)&xv[j][0] = *(const float4*)&xl[(size_t)sarr[j] * HC1 + C];
      else { xv[j][0] = 0.f; xv[j][1] = 0.f; xv[j][2] = 0.f; xv[j][3] = 0.f; }
    }
    // stage the chunk's 8 ea rows as bf16 (lanes 0-31: edge=lane>>2, quarter q=lane&3)
    {
      int me = __shfl(ev, lane >> 2);
      if (lane < 32) {
        int q = lane & 3;
        float4 u0 = *(const float4*)&ea[(size_t)me * EDGE_DIM + q * 8];
        float4 u1 = *(const float4*)&ea[(size_t)me * EDGE_DIM + q * 8 + 4];
        short* dst = &easb[wave][(lane >> 2) * 40 + q * 8];
        dst[0] = (short)f2b(u0.x); dst[1] = (short)f2b(u0.y);
        dst[2] = (short)f2b(u0.z); dst[3] = (short)f2b(u0.w);
        dst[4] = (short)f2b(u1.x); dst[5] = (short)f2b(u1.y);
        dst[6] = (short)f2b(u1.z); dst[7] = (short)f2b(u1.w);
      }
    }
    // prefetch next chunk's indices
    if (lane < 8 && i0 + 8 + lane < end) { ev = csr[i0 + 8 + lane]; sv = srcs[ev]; }
    // 16 MFMAs: A = WtT tile (read per tt), B = edge tile (read once)
    bf16x8 bfrag = *(bf16x8*)&easb[wave][l15 * 40 + l16 * 8];
    #pragma unroll 4
    for (int tt = 0; tt < 16; tt++) {
      bf16x8 afrag = *(bf16x8*)&WtT[(tt * 16 + l15) * 40 + l16 * 8];
      f32x4 cz = {0.f, 0.f, 0.f, 0.f};
      f32x4 cv = __builtin_amdgcn_mfma_f32_16x16x32_bf16(afrag, bfrag, cz, 0, 0, 0);
      if (l15 < 8) {
        ushort4 u;
        u.x = f2b(cv[0]); u.y = f2b(cv[1]); u.z = f2b(cv[2]); u.w = f2b(cv[3]);
        *(ushort4*)&ee_b[wave][l15][tt * 16 + l16 * 4] = u;
      }
    }
    // tail: logits from ee_b + xl + xr; 8 x 16-lane butterflies; defer-max softmax
    float pl[8];
    #pragma unroll
    for (int j = 0; j < 8; j++) {
      ushort4 ub = *(const ushort4*)&ee_b[wave][j][Cl];
      float z0 = b2f(ub.x) + xv[j][0] + xr4[0];
      float z1 = b2f(ub.y) + xv[j][1] + xr4[1];
      float z2 = b2f(ub.z) + xv[j][2] + xr4[2];
      float z3 = b2f(ub.w) + xv[j][3] + xr4[3];
      z0 = z0 > 0.f ? z0 : NEG_SLOPE * z0;
      z1 = z1 > 0.f ? z1 : NEG_SLOPE * z1;
      z2 = z2 > 0.f ? z2 : NEG_SLOPE * z2;
      z3 = z3 > 0.f ? z3 : NEG_SLOPE * z3;
      float s = ((z0 * at4[0] + z1 * at4[1]) + (z2 * at4[2] + z3 * at4[3]));
      #pragma unroll
      for (int o = 1; o <= 16; o <<= 1) s += __shfl_xor(s, o);
      pl[j] = (j < nv) ? s : -3.0e38f;
    }
    float cm = fmaxf(fmaxf(fmaxf(pl[0], pl[1]), fmaxf(pl[2], pl[3])),
                     fmaxf(fmaxf(pl[4], pl[5]), fmaxf(pl[6], pl[7])));
    float mn = fmaxf(mx, cm);
    if (__any(mn > mx + 8.f)) {
      float fs = __expf(mx - mn);
      dn *= fs;
      #pragma unroll
      for (int c = 0; c < 4; c++) o4[c] *= fs;
      mx = mn;
    }
    float p[8];
    #pragma unroll
    for (int j = 0; j < 8; j++) p[j] = __expf(pl[j] - mx);
    dn += ((p[0] + p[1]) + (p[2] + p[3])) + ((p[4] + p[5]) + (p[6] + p[7]));
    #pragma unroll
    for (int c = 0; c < 4; c++) {
      float acc = 0.f;
      #pragma unroll
      for (int j = 0; j < 8; j++) acc = fmaf(p[j], xv[j][c], acc);
      o4[c] += acc;
    }
  }
  float iv = dn > 0.f ? 1.f / dn : 0.f;
  float r[4];
  #pragma unroll
  for (int c = 0; c < 4; c++) {
    float v = o4[c] * iv + bias[C + c];
    r[c] = v > 0.f ? v : 0.f;            // relu after conv1
  }
  if (H1BF) {
    unsigned short* hb = (unsigned short*)h1out;
    ushort4 u;
    u.x = f2b(r[0]); u.y = f2b(r[1]); u.z = f2b(r[2]); u.w = f2b(r[3]);
    *(ushort4*)&hb[(size_t)n * HC1 + C] = u;
  } else {
    float* hf = (float*)h1out;
    *(float4*)&hf[(size_t)n * HC1 + C] = *(float4*)r;
  }
}

// ---------------- linear2 ----------------
template<bool INBF>
__global__ __launch_bounds__(256) void linear2_kernel(
    const void* __restrict__ hin_, const float* __restrict__ Wl,
    const float* __restrict__ bl, const float* __restrict__ Wr,
    const float* __restrict__ br, float* __restrict__ xl, float* __restrict__ xr)
{
  __shared__ float xsT[HC1][16];   // 32KB
  int n0 = blockIdx.x * 16;
  int t = threadIdx.x;
  for (int r = 0; r < 8; r++) {
    int flat = (t + r * 256) * 4;
    int i = flat >> 9, k = flat & 511;
    float4 v;
    if (INBF) {
      const unsigned short* hb = (const unsigned short*)hin_;
      ushort4 u = *(const ushort4*)&hb[(size_t)(n0 + i) * HC1 + k];
      v.x = b2f(u.x); v.y = b2f(u.y); v.z = b2f(u.z); v.w = b2f(u.w);
    } else {
      const float* hf = (const float*)hin_;
      v = *(const float4*)&hf[(size_t)(n0 + i) * HC1 + k];
    }
    xsT[k + 0][i] = v.x; xsT[k + 1][i] = v.y; xsT[k + 2][i] = v.z; xsT[k + 3][i] = v.w;
  }
  __syncthreads();
  int m = t >> 7, j = t & 127;
  const float* W = m ? Wr : Wl;
  float bj = (m ? br : bl)[j];
  float* out = m ? xr : xl;
  float acc[16];
  #pragma unroll
  for (int i = 0; i < 16; i++) acc[i] = 0.f;
  for (int k = 0; k < HC1; k++) {
    float w = W[k * HID + j];
    float xv[16];
    *(float4*)&xv[0]  = *(const float4*)&xsT[k][0];
    *(float4*)&xv[4]  = *(const float4*)&xsT[k][4];
    *(float4*)&xv[8]  = *(const float4*)&xsT[k][8];
    *(float4*)&xv[12] = *(const float4*)&xsT[k][12];
    #pragma unroll
    for (int i = 0; i < 16; i++) acc[i] = fmaf(xv[i], w, acc[i]);
  }
  #pragma unroll
  for (int i = 0; i < 16; i++) out[(size_t)(n0 + i) * HID + j] = acc[i] + bj;
}

// ---------------- fused layer 2 (MFMA; A=W2tT, B=edges; float4 scatter) ----------------
// block = 512 threads = 8 waves = 8 nodes. lane owns channels {2*lane, 2*lane+1}.
// D[m=ch][n=edge]: lane(l15=edge, l16) holds 4 consecutive channels -> float4 scatter.
__global__ __launch_bounds__(512, 2) void fused2_kernel(
    const float* __restrict__ ea, const int* __restrict__ srcs,
    const float* __restrict__ We, const float* __restrict__ att,
    const float* __restrict__ xl, const float* __restrict__ xr,
    const float* __restrict__ bias, const int* __restrict__ offs,
    const int* __restrict__ csr, float* __restrict__ h2out)
{
  __shared__ short W2tT[HID * 40];       // 10KB: We2 transposed [ch][k], bf16, stride 40
  __shared__ short easb2[8][16 * 40];    // 10KB: per-wave B tile, rows 0-7 real
  __shared__ float ee2[8][8][132];       // 33.8KB: per-wave ee, 8 edges x 128ch (+pad)
  int t = threadIdx.x;
  for (int i = t; i < EDGE_DIM * HID; i += 512) {
    int k = i >> 7, c = i & 127;
    W2tT[c * 40 + k] = (short)f2b(We[(size_t)k * HID + c]);
  }
  __syncthreads();
  int wave = t >> 6, lane = t & 63;
  int l15 = lane & 15, l16 = lane >> 4;
  int n = blockIdx.x * 8 + wave;
  int c = lane * 2;
  float2 atv = *(const float2*)&att[c];
  float2 xrv = *(const float2*)&xr[(size_t)n * HID + c];
  float oa = 0.f, ob = 0.f;
  float m = 8.0f, d = 0.f;
  int beg = offs[n], end = offs[n + 1];
  int ev = 0, sv = 0;
  if (lane < 8 && beg + lane < end) { ev = csr[beg + lane]; sv = srcs[ev]; }
  for (int i0 = beg; i0 < end; i0 += 8) {
    int nv = end - i0; if (nv > 8) nv = 8;
    int sarr[8];
    #pragma unroll
    for (int j = 0; j < 8; j++) sarr[j] = __shfl(sv, j);
    // issue xl gathers first (float2, coalesced across lanes)
    float2 xv[8];
    #pragma unroll
    for (int j = 0; j < 8; j++) {
      if (j < nv) xv[j] = *(const float2*)&xl[(size_t)sarr[j] * HID + c];
      else { xv[j].x = 0.f; xv[j].y = 0.f; }
    }
    // stage 8 ea rows as bf16 (lanes 0-31: edge=lane>>2, quarter q=lane&3)
    {
      int me = __shfl(ev, lane >> 2);
      if (lane < 32) {
        int q = lane & 3;
        float4 u0 = *(const float4*)&ea[(size_t)me * EDGE_DIM + q * 8];
        float4 u1 = *(const float4*)&ea[(size_t)me * EDGE_DIM + q * 8 + 4];
        short* dst = &easb2[wave][(lane >> 2) * 40 + q * 8];
        dst[0] = (short)f2b(u0.x); dst[1] = (short)f2b(u0.y);
        dst[2] = (short)f2b(u0.z); dst[3] = (short)f2b(u0.w);
        dst[4] = (short)f2b(u1.x); dst[5] = (short)f2b(u1.y);
        dst[6] = (short)f2b(u1.z); dst[7] = (short)f2b(u1.w);
      }
    }
    // prefetch next chunk's indices
    if (lane < 8 && i0 + 8 + lane < end) { ev = csr[i0 + 8 + lane]; sv = srcs[ev]; }
    // 8 MFMAs: A = W2tT tile (read per tt), B = edge tile (read once)
    bf16x8 bfrag = *(bf16x8*)&easb2[wave][l15 * 40 + l16 * 8];
    #pragma unroll 4
    for (int tt = 0; tt < 8; tt++) {
      bf16x8 afrag = *(bf16x8*)&W2tT[(tt * 16 + l15) * 40 + l16 * 8];
      f32x4 cz = {0.f, 0.f, 0.f, 0.f};
      f32x4 cv = __builtin_amdgcn_mfma_f32_16x16x32_bf16(afrag, bfrag, cz, 0, 0, 0);
      if (l15 < 8) *(float4*)&ee2[wave][l15][tt * 16 + l16 * 4] = *(float4*)&cv;
    }
    // tail: logits from ee2 + xl + xr; 8 independent 64-lane butterflies
    float pl[8];
    #pragma unroll
    for (int j = 0; j < 8; j++) {
      float2 av = *(const float2*)&ee2[wave][j][c];
      float za = av.x + xv[j].x + xrv.x;
      float zb = av.y + xv[j].y + xrv.y;
      za = za > 0.f ? za : NEG_SLOPE * za;
      zb = zb > 0.f ? zb : NEG_SLOPE * zb;
      float s = za * atv.x + zb * atv.y;
      #pragma unroll
      for (int o = 1; o < 64; o <<= 1) s += __shfl_xor(s, o);
      pl[j] = (j < nv) ? s : -3.0e38f;
    }
    float cm = fmaxf(fmaxf(fmaxf(pl[0], pl[1]), fmaxf(pl[2], pl[3])),
                     fmaxf(fmaxf(pl[4], pl[5]), fmaxf(pl[6], pl[7])));
    float mn = fmaxf(m, cm);
    if (__any(mn > m + 8.f)) {
      float fs = __expf(m - mn);
      d *= fs; oa *= fs; ob *= fs;
      m = mn;
    }
    float p[8];
    #pragma unroll
    for (int j = 0; j < 8; j++) p[j] = __expf(pl[j] - m);
    d += ((p[0] + p[1]) + (p[2] + p[3])) + ((p[4] + p[5]) + (p[6] + p[7]));
    #pragma unroll
    for (int j = 0; j < 8; j++) {
      oa = fmaf(p[j], xv[j].x, oa);
      ob = fmaf(p[j], xv[j].y, ob);
    }
  }
  float invd = d > 0.f ? 1.f / d : 0.f;
  float2 o2 = make_float2(oa * invd + bias[c], ob * invd + bias[c + 1]); // no relu after conv2
  *(float2*)&h2out[(size_t)n * HID + c] = o2;
}

// ---------------- MLP head ----------------
__global__ __launch_bounds__(256) void head_kernel(
    const float* __restrict__ h2, const float* __restrict__ Wh1,
    const float* __restrict__ bh1, const float* __restrict__ Wh2,
    const float* __restrict__ bh2, float* __restrict__ out)
{
  __shared__ float hs[16][HID];   // 8KB
  __shared__ float ts[16][64];    // 4KB
  int n0 = blockIdx.x * 16;
  int t = threadIdx.x;
  for (int r = 0; r < 2; r++) {
    int flat = (t + r * 256) * 4; // 2048 floats
    int i = flat >> 7, k = flat & 127;
    *(float4*)&hs[i][k] = *(const float4*)&h2[(size_t)(n0 + i) * HID + k];
  }
  __syncthreads();
  int j = t & 63, g = t >> 6;
  float acc[4];
  #pragma unroll
  for (int q = 0; q < 4; q++) acc[q] = 0.f;
  for (int k = 0; k < HID; k++) {
    float w = Wh1[k * 64 + j];
    #pragma unroll
    for (int q = 0; q < 4; q++) acc[q] = fmaf(hs[g + 4 * q][k], w, acc[q]);
  }
  float bj = bh1[j];
  #pragma unroll
  for (int q = 0; q < 4; q++) {
    float v = acc[q] + bj;
    ts[g + 4 * q][j] = v > 0.f ? v : 0.f;
  }
  __syncthreads();
  if (t < 32) {
    int nl = t >> 1, k = t & 1;
    float acc2 = bh2[k];
    for (int jj = 0; jj < 64; jj++) acc2 = fmaf(ts[nl][jj], Wh2[jj * 2 + k], acc2);
    out[(size_t)(n0 + nl) * 2 + k] = acc2;
  }
}

extern "C" void kernel_launch(void* const* d_in, const int* in_sizes, int n_in,
                              void* d_out, int out_size, void* d_ws, size_t ws_size,
                              hipStream_t stream)
{
  (void)in_sizes; (void)n_in; (void)out_size;
  const float* x    = (const float*)d_in[0];
  const int* eidx   = (const int*)d_in[1];
  const float* ea   = (const float*)d_in[2];
  const float* Wl1  = (const float*)d_in[3];
  const float* bl1  = (const float*)d_in[4];
  const float* Wr1  = (const float*)d_in[5];
  const float* br1  = (const float*)d_in[6];
  const float* We1  = (const float*)d_in[7];
  const float* att1 = (const float*)d_in[8];
  const float* bias1= (const float*)d_in[9];
  const float* Wl2  = (const float*)d_in[10];
  const float* bl2  = (const float*)d_in[11];
  const float* Wr2  = (const float*)d_in[12];
  const float* br2  = (const float*)d_in[13];
  const float* We2  = (const float*)d_in[14];
  const float* att2 = (const float*)d_in[15];
  const float* bias2= (const float*)d_in[16];
  const float* Wh1  = (const float*)d_in[17];
  const float* bh1  = (const float*)d_in[18];
  const float* Wh2  = (const float*)d_in[19];
  const float* bh2  = (const float*)d_in[20];
  const int* srcs = eidx;
  const int* dsts = eidx + N_EDGES;
  float* out = (float*)d_out;

  const size_t szBig = (size_t)N_NODES * HC1 * sizeof(float);
  auto aln = [](size_t b) { return (b + 511) & ~(size_t)511; };
  size_t smallSz = aln((size_t)N_NODES * 4) * 2 + aln((size_t)(N_NODES + 1) * 4)
                 + aln((size_t)N_EDGES * 4);
  size_t needF = aln(szBig) * 3 + smallSz + 4096;
  bool useBF = ws_size < needF;

  char* p = (char*)d_ws;
  auto alloc = [&](size_t bytes) { char* q = p; p += (bytes + 511) & ~(size_t)511; return q; };
  float* xl1 = (float*)alloc(szBig);
  float* xr1 = (float*)alloc(szBig);          // reused for xl2/xr2 after fused1
  void*  h1  = (void*)alloc(useBF ? szBig / 2 : szBig);
  int* deg    = (int*)alloc((size_t)N_NODES * 4);
  int* offs   = (int*)alloc((size_t)(N_NODES + 1) * 4);
  int* cursor = (int*)alloc((size_t)N_NODES * 4);
  int* csr    = (int*)alloc((size_t)N_EDGES * 4);
  float* xl2 = xr1;
  float* xr2 = xr1 + (size_t)N_NODES * HID;
  float* h2  = xl1;                            // xl1 region dead after fused1

  hipMemsetAsync(deg, 0, (size_t)N_NODES * 4, stream);
  hipLaunchKernelGGL(deg_count_kernel, dim3((N_EDGES + 255) / 256), dim3(256), 0, stream, dsts, deg);
  hipLaunchKernelGGL(scan_kernel, dim3(1), dim3(1024), 0, stream, deg, offs, cursor);
  hipLaunchKernelGGL(scatter_kernel, dim3((N_EDGES + 255) / 256), dim3(256), 0, stream, dsts, cursor, csr);
  hipLaunchKernelGGL(linear1_kernel, dim3(N_NODES / 16), dim3(256), 0, stream,
                     x, Wl1, bl1, Wr1, br1, xl1, xr1);
  // fused1: grid = (N/8 node-groups) x 2 halves
  if (useBF)
    hipLaunchKernelGGL((fused1_kernel<true>), dim3((N_NODES / 8) * 2), dim3(512), 0, stream,
                       ea, srcs, We1, att1, xl1, xr1, bias1, offs, csr, h1);
  else
    hipLaunchKernelGGL((fused1_kernel<false>), dim3((N_NODES / 8) * 2), dim3(512), 0, stream,
                       ea, srcs, We1, att1, xl1, xr1, bias1, offs, csr, h1);
  if (useBF)
    hipLaunchKernelGGL((linear2_kernel<true>), dim3(N_NODES / 16), dim3(256), 0, stream,
                       h1, Wl2, bl2, Wr2, br2, xl2, xr2);
  else
    hipLaunchKernelGGL((linear2_kernel<false>), dim3(N_NODES / 16), dim3(256), 0, stream,
                       h1, Wl2, bl2, Wr2, br2, xl2, xr2);
  hipLaunchKernelGGL(fused2_kernel, dim3(N_NODES / 8), dim3(512), 0, stream,
                     ea, srcs, We2, att2, xl2, xr2, bias2, offs, csr, h2);
  hipLaunchKernelGGL(head_kernel, dim3(N_NODES / 16), dim3(256), 0, stream,
                     h2, Wh1, bh1, Wh2, bh2, out);
}

// Round 15
// 405.809 us; speedup vs baseline: 1.6148x; 1.1816x over previous
//
#include <hip/hip_runtime.h>
#include <hip/hip_bf16.h>
#include <math.h>

#define N_NODES 20000
#define N_EDGES 320000
#define NODE_DIM 64
#define EDGE_DIM 32
#define HID 128
#define HEADS 4
#define HC1 512   // HEADS*HID
#define NEG_SLOPE 0.2f

typedef __attribute__((ext_vector_type(8))) short bf16x8;
typedef __attribute__((ext_vector_type(4))) float f32x4;

__device__ __forceinline__ unsigned short f2b(float f) {
  unsigned u = __float_as_uint(f);
  unsigned r = (u + 0x7fffu + ((u >> 16) & 1u)) >> 16;
  return (unsigned short)r;
}
__device__ __forceinline__ float b2f(unsigned short b) {
  return __uint_as_float(((unsigned)b) << 16);
}

// ---------------- CSR build ----------------
__global__ void deg_count_kernel(const int* __restrict__ dsts, int* __restrict__ deg) {
  int e = blockIdx.x * blockDim.x + threadIdx.x;
  if (e < N_EDGES) atomicAdd(&deg[dsts[e]], 1);
}

__global__ __launch_bounds__(1024) void scan_kernel(
    const int* __restrict__ deg, int* __restrict__ offs, int* __restrict__ cursor)
{
  __shared__ int part[1024];
  int t = threadIdx.x;
  const int C = 20;                 // 1024*20 = 20480 >= N_NODES
  int base = t * C;
  int loc[C]; int s = 0;
  #pragma unroll
  for (int i = 0; i < C; i++) { loc[i] = s; int idx = base + i; s += (idx < N_NODES) ? deg[idx] : 0; }
  part[t] = s;
  __syncthreads();
  for (int off = 1; off < 1024; off <<= 1) {
    int v = (t >= off) ? part[t - off] : 0;
    __syncthreads();
    part[t] += v;
    __syncthreads();
  }
  int pbase = (t > 0) ? part[t - 1] : 0;
  #pragma unroll
  for (int i = 0; i < C; i++) {
    int idx = base + i;
    if (idx < N_NODES) { int o = pbase + loc[i]; offs[idx] = o; cursor[idx] = o; }
  }
  if (t == 1023) offs[N_NODES] = part[1023];
}

__global__ void scatter_kernel(const int* __restrict__ dsts, int* __restrict__ cursor,
                               int* __restrict__ csr) {
  int e = blockIdx.x * blockDim.x + threadIdx.x;
  if (e >= N_EDGES) return;
  int pos = atomicAdd(&cursor[dsts[e]], 1);
  csr[pos] = e;
}

// ---------------- weight pre-conversion to bf16 col-major [col][k] ----------------
__global__ void wconv_kernel(const float* __restrict__ Wl1, const float* __restrict__ Wr1,
                             const float* __restrict__ Wl2, const float* __restrict__ Wr2,
                             unsigned short* __restrict__ WT1, unsigned short* __restrict__ WT2)
{
  int i = blockIdx.x * blockDim.x + threadIdx.x;
  if (i < 1024 * 64) {          // WT1: 1024 cols (Wl1|Wr1) x 64 k
    int col = i >> 6, k = i & 63;
    float v = (col < 512) ? Wl1[(size_t)k * HC1 + col] : Wr1[(size_t)k * HC1 + col - 512];
    WT1[i] = f2b(v);
  }
  if (i < 256 * 512) {          // WT2: 256 cols (Wl2|Wr2) x 512 k
    int col = i >> 9, k = i & 511;
    float v = (col < 128) ? Wl2[(size_t)k * HID + col] : Wr2[(size_t)k * HID + col - 128];
    WT2[i] = f2b(v);
  }
}

// ---------------- linear1 (MFMA): x[20000x64] @ (Wl1|Wr1) -> xl1, xr1 ----------------
// block = 256 thr = 4 waves; 16 nodes/block; wave handles cols wave*256 + tt*16.
__global__ __launch_bounds__(256, 4) void linear1_kernel(
    const float* __restrict__ x, const unsigned short* __restrict__ WT1,
    const float* __restrict__ bl, const float* __restrict__ br,
    float* __restrict__ xl, float* __restrict__ xr)
{
  __shared__ short xs[16 * 72];   // 16 nodes x 64 k (pad to 72)
  int t = threadIdx.x;
  int n0 = blockIdx.x * 16;
  {
    int i = t * 4;
    int node = i >> 6, k = i & 63;
    float4 v = *(const float4*)&x[(size_t)(n0 + node) * NODE_DIM + k];
    short* d = &xs[node * 72 + k];
    d[0] = (short)f2b(v.x); d[1] = (short)f2b(v.y);
    d[2] = (short)f2b(v.z); d[3] = (short)f2b(v.w);
  }
  __syncthreads();
  int wave = t >> 6, lane = t & 63;
  int l15 = lane & 15, l16 = lane >> 4;
  bf16x8 a0 = *(bf16x8*)&xs[l15 * 72 + 0  + l16 * 8];
  bf16x8 a1 = *(bf16x8*)&xs[l15 * 72 + 32 + l16 * 8];
  #pragma unroll 4
  for (int tt = 0; tt < 16; tt++) {
    int col = wave * 256 + tt * 16 + l15;
    const unsigned short* wp = &WT1[(size_t)col * 64 + l16 * 8];
    bf16x8 b0 = *(bf16x8*)&wp[0];
    bf16x8 b1 = *(bf16x8*)&wp[32];
    f32x4 acc = {0.f, 0.f, 0.f, 0.f};
    acc = __builtin_amdgcn_mfma_f32_16x16x32_bf16(a0, b0, acc, 0, 0, 0);
    acc = __builtin_amdgcn_mfma_f32_16x16x32_bf16(a1, b1, acc, 0, 0, 0);
    float bv = (col < 512) ? bl[col] : br[col - 512];
    float* outp = (col < 512) ? xl : xr;
    int cc = (col < 512) ? col : col - 512;
    #pragma unroll
    for (int r = 0; r < 4; r++)
      outp[(size_t)(n0 + l16 * 4 + r) * HC1 + cc] = acc[r] + bv;
  }
}

// ---------------- fused layer 1 (unchanged from R14) ----------------
template<bool H1BF>
__global__ __launch_bounds__(512, 2) void fused1_kernel(
    const float* __restrict__ ea, const int* __restrict__ srcs,
    const float* __restrict__ We, const float* __restrict__ att,
    const float* __restrict__ xl, const float* __restrict__ xr,
    const float* __restrict__ bias, const int* __restrict__ offs,
    const int* __restrict__ csr, void* __restrict__ h1out)
{
  __shared__ short WtT[256 * 40];        // 20KB
  __shared__ short easb[8][16 * 40];     // 10KB
  __shared__ short ee_b[8][8][264];      // 33KB
  int t = threadIdx.x;
  int half = blockIdx.x & 1;
  for (int i = t; i < EDGE_DIM * 256; i += 512) {
    int k = i >> 8, c = i & 255;
    WtT[c * 40 + k] = (short)f2b(We[(size_t)k * HC1 + half * 256 + c]);
  }
  __syncthreads();
  int wave = t >> 6, lane = t & 63;
  int l15 = lane & 15, l16 = lane >> 4;
  int n = (blockIdx.x >> 1) * 8 + wave;
  int Cl = lane * 4;
  int C = half * 256 + Cl;
  float at4[4], xr4[4];
  *(float4*)at4 = *(const float4*)&att[C];
  *(float4*)xr4 = *(const float4*)&xr[(size_t)n * HC1 + C];
  float o4[4] = {0.f,0.f,0.f,0.f};
  float mx = 8.0f, dn = 0.f;
  int beg = offs[n], end = offs[n + 1];
  int ev = 0, sv = 0;
  if (lane < 8 && beg + lane < end) { ev = csr[beg + lane]; sv = srcs[ev]; }
  for (int i0 = beg; i0 < end; i0 += 8) {
    int nv = end - i0; if (nv > 8) nv = 8;
    int sarr[8];
    #pragma unroll
    for (int j = 0; j < 8; j++) sarr[j] = __shfl(sv, j);
    float xv[8][4];
    #pragma unroll
    for (int j = 0; j < 8; j++) {
      if (j < nv) *(float4*)&xv[j][0] = *(const float4*)&xl[(size_t)sarr[j] * HC1 + C];
      else { xv[j][0] = 0.f; xv[j][1] = 0.f; xv[j][2] = 0.f; xv[j][3] = 0.f; }
    }
    {
      int me = __shfl(ev, lane >> 2);
      if (lane < 32) {
        int q = lane & 3;
        float4 u0 = *(const float4*)&ea[(size_t)me * EDGE_DIM + q * 8];
        float4 u1 = *(const float4*)&ea[(size_t)me * EDGE_DIM + q * 8 + 4];
        short* dst = &easb[wave][(lane >> 2) * 40 + q * 8];
        dst[0] = (short)f2b(u0.x); dst[1] = (short)f2b(u0.y);
        dst[2] = (short)f2b(u0.z); dst[3] = (short)f2b(u0.w);
        dst[4] = (short)f2b(u1.x); dst[5] = (short)f2b(u1.y);
        dst[6] = (short)f2b(u1.z); dst[7] = (short)f2b(u1.w);
      }
    }
    if (lane < 8 && i0 + 8 + lane < end) { ev = csr[i0 + 8 + lane]; sv = srcs[ev]; }
    bf16x8 bfrag = *(bf16x8*)&easb[wave][l15 * 40 + l16 * 8];
    #pragma unroll 4
    for (int tt = 0; tt < 16; tt++) {
      bf16x8 afrag = *(bf16x8*)&WtT[(tt * 16 + l15) * 40 + l16 * 8];
      f32x4 cz = {0.f, 0.f, 0.f, 0.f};
      f32x4 cv = __builtin_amdgcn_mfma_f32_16x16x32_bf16(afrag, bfrag, cz, 0, 0, 0);
      if (l15 < 8) {
        ushort4 u;
        u.x = f2b(cv[0]); u.y = f2b(cv[1]); u.z = f2b(cv[2]); u.w = f2b(cv[3]);
        *(ushort4*)&ee_b[wave][l15][tt * 16 + l16 * 4] = u;
      }
    }
    float pl[8];
    #pragma unroll
    for (int j = 0; j < 8; j++) {
      ushort4 ub = *(const ushort4*)&ee_b[wave][j][Cl];
      float z0 = b2f(ub.x) + xv[j][0] + xr4[0];
      float z1 = b2f(ub.y) + xv[j][1] + xr4[1];
      float z2 = b2f(ub.z) + xv[j][2] + xr4[2];
      float z3 = b2f(ub.w) + xv[j][3] + xr4[3];
      z0 = z0 > 0.f ? z0 : NEG_SLOPE * z0;
      z1 = z1 > 0.f ? z1 : NEG_SLOPE * z1;
      z2 = z2 > 0.f ? z2 : NEG_SLOPE * z2;
      z3 = z3 > 0.f ? z3 : NEG_SLOPE * z3;
      float s = ((z0 * at4[0] + z1 * at4[1]) + (z2 * at4[2] + z3 * at4[3]));
      #pragma unroll
      for (int o = 1; o <= 16; o <<= 1) s += __shfl_xor(s, o);
      pl[j] = (j < nv) ? s : -3.0e38f;
    }
    float cm = fmaxf(fmaxf(fmaxf(pl[0], pl[1]), fmaxf(pl[2], pl[3])),
                     fmaxf(fmaxf(pl[4], pl[5]), fmaxf(pl[6], pl[7])));
    float mn = fmaxf(mx, cm);
    if (__any(mn > mx + 8.f)) {
      float fs = __expf(mx - mn);
      dn *= fs;
      #pragma unroll
      for (int c = 0; c < 4; c++) o4[c] *= fs;
      mx = mn;
    }
    float p[8];
    #pragma unroll
    for (int j = 0; j < 8; j++) p[j] = __expf(pl[j] - mx);
    dn += ((p[0] + p[1]) + (p[2] + p[3])) + ((p[4] + p[5]) + (p[6] + p[7]));
    #pragma unroll
    for (int c = 0; c < 4; c++) {
      float acc = 0.f;
      #pragma unroll
      for (int j = 0; j < 8; j++) acc = fmaf(p[j], xv[j][c], acc);
      o4[c] += acc;
    }
  }
  float iv = dn > 0.f ? 1.f / dn : 0.f;
  float r[4];
  #pragma unroll
  for (int c = 0; c < 4; c++) {
    float v = o4[c] * iv + bias[C + c];
    r[c] = v > 0.f ? v : 0.f;            // relu after conv1
  }
  if (H1BF) {
    unsigned short* hb = (unsigned short*)h1out;
    ushort4 u;
    u.x = f2b(r[0]); u.y = f2b(r[1]); u.z = f2b(r[2]); u.w = f2b(r[3]);
    *(ushort4*)&hb[(size_t)n * HC1 + C] = u;
  } else {
    float* hf = (float*)h1out;
    *(float4*)&hf[(size_t)n * HC1 + C] = *(float4*)r;
  }
}

// ---------------- linear2 (MFMA): h1[20000x512] @ (Wl2|Wr2) -> xl2, xr2 ----------------
// block = 256 thr = 4 waves; 16 nodes/block; wave handles cols wave*64 + tt*16.
template<bool INBF>
__global__ __launch_bounds__(256, 4) void linear2_kernel(
    const void* __restrict__ hin_, const unsigned short* __restrict__ WT2,
    const float* __restrict__ bl, const float* __restrict__ br,
    float* __restrict__ xl, float* __restrict__ xr)
{
  __shared__ short hs[16 * 520];   // 16 nodes x 512 k (pad to 520) bf16 = 16.6KB
  int t = threadIdx.x;
  int n0 = blockIdx.x * 16;
  for (int rr = 0; rr < 8; rr++) {
    int i = (t + rr * 256) * 4;
    int node = i >> 9, k = i & 511;
    short* d = &hs[node * 520 + k];
    if (INBF) {
      ushort4 u = *(const ushort4*)&((const unsigned short*)hin_)[(size_t)(n0 + node) * HC1 + k];
      d[0] = (short)u.x; d[1] = (short)u.y; d[2] = (short)u.z; d[3] = (short)u.w;
    } else {
      float4 v = *(const float4*)&((const float*)hin_)[(size_t)(n0 + node) * HC1 + k];
      d[0] = (short)f2b(v.x); d[1] = (short)f2b(v.y);
      d[2] = (short)f2b(v.z); d[3] = (short)f2b(v.w);
    }
  }
  __syncthreads();
  int wave = t >> 6, lane = t & 63;
  int l15 = lane & 15, l16 = lane >> 4;
  f32x4 acc0 = {0.f,0.f,0.f,0.f}, acc1 = {0.f,0.f,0.f,0.f};
  f32x4 acc2 = {0.f,0.f,0.f,0.f}, acc3 = {0.f,0.f,0.f,0.f};
  int colb = wave * 64 + l15;
  #pragma unroll 2
  for (int ks = 0; ks < 16; ks++) {
    bf16x8 a = *(bf16x8*)&hs[l15 * 520 + ks * 32 + l16 * 8];
    bf16x8 b0 = *(bf16x8*)&WT2[(size_t)(colb +  0) * 512 + ks * 32 + l16 * 8];
    bf16x8 b1 = *(bf16x8*)&WT2[(size_t)(colb + 16) * 512 + ks * 32 + l16 * 8];
    bf16x8 b2 = *(bf16x8*)&WT2[(size_t)(colb + 32) * 512 + ks * 32 + l16 * 8];
    bf16x8 b3 = *(bf16x8*)&WT2[(size_t)(colb + 48) * 512 + ks * 32 + l16 * 8];
    acc0 = __builtin_amdgcn_mfma_f32_16x16x32_bf16(a, b0, acc0, 0, 0, 0);
    acc1 = __builtin_amdgcn_mfma_f32_16x16x32_bf16(a, b1, acc1, 0, 0, 0);
    acc2 = __builtin_amdgcn_mfma_f32_16x16x32_bf16(a, b2, acc2, 0, 0, 0);
    acc3 = __builtin_amdgcn_mfma_f32_16x16x32_bf16(a, b3, acc3, 0, 0, 0);
  }
  #pragma unroll
  for (int tt = 0; tt < 4; tt++) {
    const f32x4* ap = (tt == 0) ? &acc0 : (tt == 1) ? &acc1 : (tt == 2) ? &acc2 : &acc3;
    int col = wave * 64 + tt * 16 + l15;
    float bv = (col < 128) ? bl[col] : br[col - 128];
    float* outp = (col < 128) ? xl : xr;
    int cc = (col < 128) ? col : col - 128;
    #pragma unroll
    for (int r = 0; r < 4; r++)
      outp[(size_t)(n0 + l16 * 4 + r) * HID + cc] = (*ap)[r] + bv;
  }
}

// ---------------- fused layer 2 (unchanged from R14) ----------------
__global__ __launch_bounds__(512, 2) void fused2_kernel(
    const float* __restrict__ ea, const int* __restrict__ srcs,
    const float* __restrict__ We, const float* __restrict__ att,
    const float* __restrict__ xl, const float* __restrict__ xr,
    const float* __restrict__ bias, const int* __restrict__ offs,
    const int* __restrict__ csr, float* __restrict__ h2out)
{
  __shared__ short W2tT[HID * 40];       // 10KB
  __shared__ short easb2[8][16 * 40];    // 10KB
  __shared__ float ee2[8][8][132];       // 33.8KB
  int t = threadIdx.x;
  for (int i = t; i < EDGE_DIM * HID; i += 512) {
    int k = i >> 7, c = i & 127;
    W2tT[c * 40 + k] = (short)f2b(We[(size_t)k * HID + c]);
  }
  __syncthreads();
  int wave = t >> 6, lane = t & 63;
  int l15 = lane & 15, l16 = lane >> 4;
  int n = blockIdx.x * 8 + wave;
  int c = lane * 2;
  float2 atv = *(const float2*)&att[c];
  float2 xrv = *(const float2*)&xr[(size_t)n * HID + c];
  float oa = 0.f, ob = 0.f;
  float m = 8.0f, d = 0.f;
  int beg = offs[n], end = offs[n + 1];
  int ev = 0, sv = 0;
  if (lane < 8 && beg + lane < end) { ev = csr[beg + lane]; sv = srcs[ev]; }
  for (int i0 = beg; i0 < end; i0 += 8) {
    int nv = end - i0; if (nv > 8) nv = 8;
    int sarr[8];
    #pragma unroll
    for (int j = 0; j < 8; j++) sarr[j] = __shfl(sv, j);
    float2 xv[8];
    #pragma unroll
    for (int j = 0; j < 8; j++) {
      if (j < nv) xv[j] = *(const float2*)&xl[(size_t)sarr[j] * HID + c];
      else { xv[j].x = 0.f; xv[j].y = 0.f; }
    }
    {
      int me = __shfl(ev, lane >> 2);
      if (lane < 32) {
        int q = lane & 3;
        float4 u0 = *(const float4*)&ea[(size_t)me * EDGE_DIM + q * 8];
        float4 u1 = *(const float4*)&ea[(size_t)me * EDGE_DIM + q * 8 + 4];
        short* dst = &easb2[wave][(lane >> 2) * 40 + q * 8];
        dst[0] = (short)f2b(u0.x); dst[1] = (short)f2b(u0.y);
        dst[2] = (short)f2b(u0.z); dst[3] = (short)f2b(u0.w);
        dst[4] = (short)f2b(u1.x); dst[5] = (short)f2b(u1.y);
        dst[6] = (short)f2b(u1.z); dst[7] = (short)f2b(u1.w);
      }
    }
    if (lane < 8 && i0 + 8 + lane < end) { ev = csr[i0 + 8 + lane]; sv = srcs[ev]; }
    bf16x8 bfrag = *(bf16x8*)&easb2[wave][l15 * 40 + l16 * 8];
    #pragma unroll 4
    for (int tt = 0; tt < 8; tt++) {
      bf16x8 afrag = *(bf16x8*)&W2tT[(tt * 16 + l15) * 40 + l16 * 8];
      f32x4 cz = {0.f, 0.f, 0.f, 0.f};
      f32x4 cv = __builtin_amdgcn_mfma_f32_16x16x32_bf16(afrag, bfrag, cz, 0, 0, 0);
      if (l15 < 8) *(float4*)&ee2[wave][l15][tt * 16 + l16 * 4] = *(float4*)&cv;
    }
    float pl[8];
    #pragma unroll
    for (int j = 0; j < 8; j++) {
      float2 av = *(const float2*)&ee2[wave][j][c];
      float za = av.x + xv[j].x + xrv.x;
      float zb = av.y + xv[j].y + xrv.y;
      za = za > 0.f ? za : NEG_SLOPE * za;
      zb = zb > 0.f ? zb : NEG_SLOPE * zb;
      float s = za * atv.x + zb * atv.y;
      #pragma unroll
      for (int o = 1; o < 64; o <<= 1) s += __shfl_xor(s, o);
      pl[j] = (j < nv) ? s : -3.0e38f;
    }
    float cm = fmaxf(fmaxf(fmaxf(pl[0], pl[1]), fmaxf(pl[2], pl[3])),
                     fmaxf(fmaxf(pl[4], pl[5]), fmaxf(pl[6], pl[7])));
    float mn = fmaxf(m, cm);
    if (__any(mn > m + 8.f)) {
      float fs = __expf(m - mn);
      d *= fs; oa *= fs; ob *= fs;
      m = mn;
    }
    float p[8];
    #pragma unroll
    for (int j = 0; j < 8; j++) p[j] = __expf(pl[j] - m);
    d += ((p[0] + p[1]) + (p[2] + p[3])) + ((p[4] + p[5]) + (p[6] + p[7]));
    #pragma unroll
    for (int j = 0; j < 8; j++) {
      oa = fmaf(p[j], xv[j].x, oa);
      ob = fmaf(p[j], xv[j].y, ob);
    }
  }
  float invd = d > 0.f ? 1.f / d : 0.f;
  float2 o2 = make_float2(oa * invd + bias[c], ob * invd + bias[c + 1]); // no relu after conv2
  *(float2*)&h2out[(size_t)n * HID + c] = o2;
}

// ---------------- MLP head ----------------
__global__ __launch_bounds__(256) void head_kernel(
    const float* __restrict__ h2, const float* __restrict__ Wh1,
    const float* __restrict__ bh1, const float* __restrict__ Wh2,
    const float* __restrict__ bh2, float* __restrict__ out)
{
  __shared__ float hs[16][HID];   // 8KB
  __shared__ float ts[16][64];    // 4KB
  int n0 = blockIdx.x * 16;
  int t = threadIdx.x;
  for (int r = 0; r < 2; r++) {
    int flat = (t + r * 256) * 4; // 2048 floats
    int i = flat >> 7, k = flat & 127;
    *(float4*)&hs[i][k] = *(const float4*)&h2[(size_t)(n0 + i) * HID + k];
  }
  __syncthreads();
  int j = t & 63, g = t >> 6;
  float acc[4];
  #pragma unroll
  for (int q = 0; q < 4; q++) acc[q] = 0.f;
  for (int k = 0; k < HID; k++) {
    float w = Wh1[k * 64 + j];
    #pragma unroll
    for (int q = 0; q < 4; q++) acc[q] = fmaf(hs[g + 4 * q][k], w, acc[q]);
  }
  float bj = bh1[j];
  #pragma unroll
  for (int q = 0; q < 4; q++) {
    float v = acc[q] + bj;
    ts[g + 4 * q][j] = v > 0.f ? v : 0.f;
  }
  __syncthreads();
  if (t < 32) {
    int nl = t >> 1, k = t & 1;
    float acc2 = bh2[k];
    for (int jj = 0; jj < 64; jj++) acc2 = fmaf(ts[nl][jj], Wh2[jj * 2 + k], acc2);
    out[(size_t)(n0 + nl) * 2 + k] = acc2;
  }
}

extern "C" void kernel_launch(void* const* d_in, const int* in_sizes, int n_in,
                              void* d_out, int out_size, void* d_ws, size_t ws_size,
                              hipStream_t stream)
{
  (void)in_sizes; (void)n_in; (void)out_size;
  const float* x    = (const float*)d_in[0];
  const int* eidx   = (const int*)d_in[1];
  const float* ea   = (const float*)d_in[2];
  const float* Wl1  = (const float*)d_in[3];
  const float* bl1  = (const float*)d_in[4];
  const float* Wr1  = (const float*)d_in[5];
  const float* br1  = (const float*)d_in[6];
  const float* We1  = (const float*)d_in[7];
  const float* att1 = (const float*)d_in[8];
  const float* bias1= (const float*)d_in[9];
  const float* Wl2  = (const float*)d_in[10];
  const float* bl2  = (const float*)d_in[11];
  const float* Wr2  = (const float*)d_in[12];
  const float* br2  = (const float*)d_in[13];
  const float* We2  = (const float*)d_in[14];
  const float* att2 = (const float*)d_in[15];
  const float* bias2= (const float*)d_in[16];
  const float* Wh1  = (const float*)d_in[17];
  const float* bh1  = (const float*)d_in[18];
  const float* Wh2  = (const float*)d_in[19];
  const float* bh2  = (const float*)d_in[20];
  const int* srcs = eidx;
  const int* dsts = eidx + N_EDGES;
  float* out = (float*)d_out;

  const size_t szBig = (size_t)N_NODES * HC1 * sizeof(float);
  auto aln = [](size_t b) { return (b + 511) & ~(size_t)511; };
  size_t smallSz = aln((size_t)N_NODES * 4) * 2 + aln((size_t)(N_NODES + 1) * 4)
                 + aln((size_t)N_EDGES * 4) + aln(1024 * 64 * 2) + aln(256 * 512 * 2);
  size_t needF = aln(szBig) * 3 + smallSz + 4096;
  bool useBF = ws_size < needF;

  char* p = (char*)d_ws;
  auto alloc = [&](size_t bytes) { char* q = p; p += (bytes + 511) & ~(size_t)511; return q; };
  float* xl1 = (float*)alloc(szBig);
  float* xr1 = (float*)alloc(szBig);          // reused for xl2/xr2 after fused1
  void*  h1  = (void*)alloc(useBF ? szBig / 2 : szBig);
  int* deg    = (int*)alloc((size_t)N_NODES * 4);
  int* offs   = (int*)alloc((size_t)(N_NODES + 1) * 4);
  int* cursor = (int*)alloc((size_t)N_NODES * 4);
  int* csr    = (int*)alloc((size_t)N_EDGES * 4);
  unsigned short* WT1 = (unsigned short*)alloc(1024 * 64 * 2);
  unsigned short* WT2 = (unsigned short*)alloc(256 * 512 * 2);
  float* xl2 = xr1;
  float* xr2 = xr1 + (size_t)N_NODES * HID;
  float* h2  = xl1;                            // xl1 region dead after fused1

  hipMemsetAsync(deg, 0, (size_t)N_NODES * 4, stream);
  hipLaunchKernelGGL(deg_count_kernel, dim3((N_EDGES + 255) / 256), dim3(256), 0, stream, dsts, deg);
  hipLaunchKernelGGL(wconv_kernel, dim3(512), dim3(256), 0, stream, Wl1, Wr1, Wl2, Wr2, WT1, WT2);
  hipLaunchKernelGGL(scan_kernel, dim3(1), dim3(1024), 0, stream, deg, offs, cursor);
  hipLaunchKernelGGL(scatter_kernel, dim3((N_EDGES + 255) / 256), dim3(256), 0, stream, dsts, cursor, csr);
  hipLaunchKernelGGL(linear1_kernel, dim3(N_NODES / 16), dim3(256), 0, stream,
                     x, WT1, bl1, br1, xl1, xr1);
  // fused1: grid = (N/8 node-groups) x 2 halves
  if (useBF)
    hipLaunchKernelGGL((fused1_kernel<true>), dim3((N_NODES / 8) * 2), dim3(512), 0, stream,
                       ea, srcs, We1, att1, xl1, xr1, bias1, offs, csr, h1);
  else
    hipLaunchKernelGGL((fused1_kernel<false>), dim3((N_NODES / 8) * 2), dim3(512), 0, stream,
                       ea, srcs, We1, att1, xl1, xr1, bias1, offs, csr, h1);
  if (useBF)
    hipLaunchKernelGGL((linear2_kernel<true>), dim3(N_NODES / 16), dim3(256), 0, stream,
                       h1, WT2, bl2, br2, xl2, xr2);
  else
    hipLaunchKernelGGL((linear2_kernel<false>), dim3(N_NODES / 16), dim3(256), 0, stream,
                       h1, WT2, bl2, br2, xl2, xr2);
  hipLaunchKernelGGL(fused2_kernel, dim3(N_NODES / 8), dim3(512), 0, stream,
                     ea, srcs, We2, att2, xl2, xr2, bias2, offs, csr, h2);
  hipLaunchKernelGGL(head_kernel, dim3(N_NODES / 16), dim3(256), 0, stream,
                     h2, Wh1, bh1, Wh2, bh2, out);
}

// Round 16
// 388.623 us; speedup vs baseline: 1.6863x; 1.0442x over previous
//
#include <hip/hip_runtime.h>
#include <hip/hip_bf16.h>
#include <math.h>

#define N_NODES 20000
#define N_EDGES 320000
#define NODE_DIM 64
#define EDGE_DIM 32
#define HID 128
#define HEADS 4
#define HC1 512   // HEADS*HID
#define NEG_SLOPE 0.2f

typedef __attribute__((ext_vector_type(8))) short bf16x8;
typedef __attribute__((ext_vector_type(4))) float f32x4;

// hardware bf16 convert (RNE) — compiler emits v_cvt_pk_bf16_f32 for pairs
__device__ __forceinline__ unsigned short f2b(float f) {
  __hip_bfloat16 h = __float2bfloat16(f);
  unsigned short s;
  __builtin_memcpy(&s, &h, 2);
  return s;
}
__device__ __forceinline__ float b2f(unsigned short b) {
  return __uint_as_float(((unsigned)b) << 16);
}

// ---------------- CSR build ----------------
__global__ void deg_count_kernel(const int* __restrict__ dsts, int* __restrict__ deg) {
  int e = blockIdx.x * blockDim.x + threadIdx.x;
  if (e < N_EDGES) atomicAdd(&deg[dsts[e]], 1);
}

__global__ __launch_bounds__(1024) void scan_kernel(
    const int* __restrict__ deg, int* __restrict__ offs, int* __restrict__ cursor)
{
  __shared__ int part[1024];
  int t = threadIdx.x;
  const int C = 20;                 // 1024*20 = 20480 >= N_NODES
  int base = t * C;
  int loc[C]; int s = 0;
  #pragma unroll
  for (int i = 0; i < C; i++) { loc[i] = s; int idx = base + i; s += (idx < N_NODES) ? deg[idx] : 0; }
  part[t] = s;
  __syncthreads();
  for (int off = 1; off < 1024; off <<= 1) {
    int v = (t >= off) ? part[t - off] : 0;
    __syncthreads();
    part[t] += v;
    __syncthreads();
  }
  int pbase = (t > 0) ? part[t - 1] : 0;
  #pragma unroll
  for (int i = 0; i < C; i++) {
    int idx = base + i;
    if (idx < N_NODES) { int o = pbase + loc[i]; offs[idx] = o; cursor[idx] = o; }
  }
  if (t == 1023) offs[N_NODES] = part[1023];
}

__global__ void scatter_kernel(const int* __restrict__ dsts, int* __restrict__ cursor,
                               int* __restrict__ csr) {
  int e = blockIdx.x * blockDim.x + threadIdx.x;
  if (e >= N_EDGES) return;
  int pos = atomicAdd(&cursor[dsts[e]], 1);
  csr[pos] = e;
}

// ---------------- weight pre-conversion to bf16 col-major [col][k] ----------------
__global__ void wconv_kernel(const float* __restrict__ Wl1, const float* __restrict__ Wr1,
                             const float* __restrict__ Wl2, const float* __restrict__ Wr2,
                             unsigned short* __restrict__ WT1, unsigned short* __restrict__ WT2)
{
  int i = blockIdx.x * blockDim.x + threadIdx.x;
  if (i < 1024 * 64) {          // WT1: 1024 cols (Wl1|Wr1) x 64 k
    int col = i >> 6, k = i & 63;
    float v = (col < 512) ? Wl1[(size_t)k * HC1 + col] : Wr1[(size_t)k * HC1 + col - 512];
    WT1[i] = f2b(v);
  }
  if (i < 256 * 512) {          // WT2: 256 cols (Wl2|Wr2) x 512 k
    int col = i >> 9, k = i & 511;
    float v = (col < 128) ? Wl2[(size_t)k * HID + col] : Wr2[(size_t)k * HID + col - 128];
    WT2[i] = f2b(v);
  }
}

// ---------------- linear1 (MFMA) ----------------
__global__ __launch_bounds__(256, 4) void linear1_kernel(
    const float* __restrict__ x, const unsigned short* __restrict__ WT1,
    const float* __restrict__ bl, const float* __restrict__ br,
    float* __restrict__ xl, float* __restrict__ xr)
{
  __shared__ short xs[16 * 72];   // 16 nodes x 64 k (pad to 72)
  int t = threadIdx.x;
  int n0 = blockIdx.x * 16;
  {
    int i = t * 4;
    int node = i >> 6, k = i & 63;
    float4 v = *(const float4*)&x[(size_t)(n0 + node) * NODE_DIM + k];
    short* d = &xs[node * 72 + k];
    d[0] = (short)f2b(v.x); d[1] = (short)f2b(v.y);
    d[2] = (short)f2b(v.z); d[3] = (short)f2b(v.w);
  }
  __syncthreads();
  int wave = t >> 6, lane = t & 63;
  int l15 = lane & 15, l16 = lane >> 4;
  bf16x8 a0 = *(bf16x8*)&xs[l15 * 72 + 0  + l16 * 8];
  bf16x8 a1 = *(bf16x8*)&xs[l15 * 72 + 32 + l16 * 8];
  #pragma unroll 4
  for (int tt = 0; tt < 16; tt++) {
    int col = wave * 256 + tt * 16 + l15;
    const unsigned short* wp = &WT1[(size_t)col * 64 + l16 * 8];
    bf16x8 b0 = *(bf16x8*)&wp[0];
    bf16x8 b1 = *(bf16x8*)&wp[32];
    f32x4 acc = {0.f, 0.f, 0.f, 0.f};
    acc = __builtin_amdgcn_mfma_f32_16x16x32_bf16(a0, b0, acc, 0, 0, 0);
    acc = __builtin_amdgcn_mfma_f32_16x16x32_bf16(a1, b1, acc, 0, 0, 0);
    float bv = (col < 512) ? bl[col] : br[col - 512];
    float* outp = (col < 512) ? xl : xr;
    int cc = (col < 512) ? col : col - 512;
    #pragma unroll
    for (int r = 0; r < 4; r++)
      outp[(size_t)(n0 + l16 * 4 + r) * HC1 + cc] = acc[r] + bv;
  }
}

// ---------------- fused layer 1 (unchanged structure; fast converts) ----------------
template<bool H1BF>
__global__ __launch_bounds__(512, 2) void fused1_kernel(
    const float* __restrict__ ea, const int* __restrict__ srcs,
    const float* __restrict__ We, const float* __restrict__ att,
    const float* __restrict__ xl, const float* __restrict__ xr,
    const float* __restrict__ bias, const int* __restrict__ offs,
    const int* __restrict__ csr, void* __restrict__ h1out)
{
  __shared__ short WtT[256 * 40];        // 20KB
  __shared__ short easb[8][16 * 40];     // 10KB
  __shared__ short ee_b[8][8][264];      // 33KB
  int t = threadIdx.x;
  int half = blockIdx.x & 1;
  for (int i = t; i < EDGE_DIM * 256; i += 512) {
    int k = i >> 8, c = i & 255;
    WtT[c * 40 + k] = (short)f2b(We[(size_t)k * HC1 + half * 256 + c]);
  }
  __syncthreads();
  int wave = t >> 6, lane = t & 63;
  int l15 = lane & 15, l16 = lane >> 4;
  int n = (blockIdx.x >> 1) * 8 + wave;
  int Cl = lane * 4;
  int C = half * 256 + Cl;
  float at4[4], xr4[4];
  *(float4*)at4 = *(const float4*)&att[C];
  *(float4*)xr4 = *(const float4*)&xr[(size_t)n * HC1 + C];
  float o4[4] = {0.f,0.f,0.f,0.f};
  float mx = 8.0f, dn = 0.f;
  int beg = offs[n], end = offs[n + 1];
  int ev = 0, sv = 0;
  if (lane < 8 && beg + lane < end) { ev = csr[beg + lane]; sv = srcs[ev]; }
  for (int i0 = beg; i0 < end; i0 += 8) {
    int nv = end - i0; if (nv > 8) nv = 8;
    int sarr[8];
    #pragma unroll
    for (int j = 0; j < 8; j++) sarr[j] = __shfl(sv, j);
    float xv[8][4];
    #pragma unroll
    for (int j = 0; j < 8; j++) {
      if (j < nv) *(float4*)&xv[j][0] = *(const float4*)&xl[(size_t)sarr[j] * HC1 + C];
      else { xv[j][0] = 0.f; xv[j][1] = 0.f; xv[j][2] = 0.f; xv[j][3] = 0.f; }
    }
    {
      int me = __shfl(ev, lane >> 2);
      if (lane < 32) {
        int q = lane & 3;
        float4 u0 = *(const float4*)&ea[(size_t)me * EDGE_DIM + q * 8];
        float4 u1 = *(const float4*)&ea[(size_t)me * EDGE_DIM + q * 8 + 4];
        short* dst = &easb[wave][(lane >> 2) * 40 + q * 8];
        dst[0] = (short)f2b(u0.x); dst[1] = (short)f2b(u0.y);
        dst[2] = (short)f2b(u0.z); dst[3] = (short)f2b(u0.w);
        dst[4] = (short)f2b(u1.x); dst[5] = (short)f2b(u1.y);
        dst[6] = (short)f2b(u1.z); dst[7] = (short)f2b(u1.w);
      }
    }
    if (lane < 8 && i0 + 8 + lane < end) { ev = csr[i0 + 8 + lane]; sv = srcs[ev]; }
    bf16x8 bfrag = *(bf16x8*)&easb[wave][l15 * 40 + l16 * 8];
    #pragma unroll 4
    for (int tt = 0; tt < 16; tt++) {
      bf16x8 afrag = *(bf16x8*)&WtT[(tt * 16 + l15) * 40 + l16 * 8];
      f32x4 cz = {0.f, 0.f, 0.f, 0.f};
      f32x4 cv = __builtin_amdgcn_mfma_f32_16x16x32_bf16(afrag, bfrag, cz, 0, 0, 0);
      if (l15 < 8) {
        ushort4 u;
        u.x = f2b(cv[0]); u.y = f2b(cv[1]); u.z = f2b(cv[2]); u.w = f2b(cv[3]);
        *(ushort4*)&ee_b[wave][l15][tt * 16 + l16 * 4] = u;
      }
    }
    float pl[8];
    #pragma unroll
    for (int j = 0; j < 8; j++) {
      ushort4 ub = *(const ushort4*)&ee_b[wave][j][Cl];
      float z0 = b2f(ub.x) + xv[j][0] + xr4[0];
      float z1 = b2f(ub.y) + xv[j][1] + xr4[1];
      float z2 = b2f(ub.z) + xv[j][2] + xr4[2];
      float z3 = b2f(ub.w) + xv[j][3] + xr4[3];
      z0 = z0 > 0.f ? z0 : NEG_SLOPE * z0;
      z1 = z1 > 0.f ? z1 : NEG_SLOPE * z1;
      z2 = z2 > 0.f ? z2 : NEG_SLOPE * z2;
      z3 = z3 > 0.f ? z3 : NEG_SLOPE * z3;
      float s = ((z0 * at4[0] + z1 * at4[1]) + (z2 * at4[2] + z3 * at4[3]));
      #pragma unroll
      for (int o = 1; o <= 16; o <<= 1) s += __shfl_xor(s, o);
      pl[j] = (j < nv) ? s : -3.0e38f;
    }
    float cm = fmaxf(fmaxf(fmaxf(pl[0], pl[1]), fmaxf(pl[2], pl[3])),
                     fmaxf(fmaxf(pl[4], pl[5]), fmaxf(pl[6], pl[7])));
    float mn = fmaxf(mx, cm);
    if (__any(mn > mx + 8.f)) {
      float fs = __expf(mx - mn);
      dn *= fs;
      #pragma unroll
      for (int c = 0; c < 4; c++) o4[c] *= fs;
      mx = mn;
    }
    float p[8];
    #pragma unroll
    for (int j = 0; j < 8; j++) p[j] = __expf(pl[j] - mx);
    dn += ((p[0] + p[1]) + (p[2] + p[3])) + ((p[4] + p[5]) + (p[6] + p[7]));
    #pragma unroll
    for (int c = 0; c < 4; c++) {
      float acc = 0.f;
      #pragma unroll
      for (int j = 0; j < 8; j++) acc = fmaf(p[j], xv[j][c], acc);
      o4[c] += acc;
    }
  }
  float iv = dn > 0.f ? 1.f / dn : 0.f;
  float r[4];
  #pragma unroll
  for (int c = 0; c < 4; c++) {
    float v = o4[c] * iv + bias[C + c];
    r[c] = v > 0.f ? v : 0.f;            // relu after conv1
  }
  if (H1BF) {
    unsigned short* hb = (unsigned short*)h1out;
    ushort4 u;
    u.x = f2b(r[0]); u.y = f2b(r[1]); u.z = f2b(r[2]); u.w = f2b(r[3]);
    *(ushort4*)&hb[(size_t)n * HC1 + C] = u;
  } else {
    float* hf = (float*)h1out;
    *(float4*)&hf[(size_t)n * HC1 + C] = *(float4*)r;
  }
}

// ---------------- linear2 (MFMA) ----------------
template<bool INBF>
__global__ __launch_bounds__(256, 4) void linear2_kernel(
    const void* __restrict__ hin_, const unsigned short* __restrict__ WT2,
    const float* __restrict__ bl, const float* __restrict__ br,
    float* __restrict__ xl, float* __restrict__ xr)
{
  __shared__ short hs[16 * 520];   // 16 nodes x 512 k (pad to 520) bf16 = 16.6KB
  int t = threadIdx.x;
  int n0 = blockIdx.x * 16;
  for (int rr = 0; rr < 8; rr++) {
    int i = (t + rr * 256) * 4;
    int node = i >> 9, k = i & 511;
    short* d = &hs[node * 520 + k];
    if (INBF) {
      ushort4 u = *(const ushort4*)&((const unsigned short*)hin_)[(size_t)(n0 + node) * HC1 + k];
      d[0] = (short)u.x; d[1] = (short)u.y; d[2] = (short)u.z; d[3] = (short)u.w;
    } else {
      float4 v = *(const float4*)&((const float*)hin_)[(size_t)(n0 + node) * HC1 + k];
      d[0] = (short)f2b(v.x); d[1] = (short)f2b(v.y);
      d[2] = (short)f2b(v.z); d[3] = (short)f2b(v.w);
    }
  }
  __syncthreads();
  int wave = t >> 6, lane = t & 63;
  int l15 = lane & 15, l16 = lane >> 4;
  f32x4 acc0 = {0.f,0.f,0.f,0.f}, acc1 = {0.f,0.f,0.f,0.f};
  f32x4 acc2 = {0.f,0.f,0.f,0.f}, acc3 = {0.f,0.f,0.f,0.f};
  int colb = wave * 64 + l15;
  #pragma unroll 2
  for (int ks = 0; ks < 16; ks++) {
    bf16x8 a = *(bf16x8*)&hs[l15 * 520 + ks * 32 + l16 * 8];
    bf16x8 b0 = *(bf16x8*)&WT2[(size_t)(colb +  0) * 512 + ks * 32 + l16 * 8];
    bf16x8 b1 = *(bf16x8*)&WT2[(size_t)(colb + 16) * 512 + ks * 32 + l16 * 8];
    bf16x8 b2 = *(bf16x8*)&WT2[(size_t)(colb + 32) * 512 + ks * 32 + l16 * 8];
    bf16x8 b3 = *(bf16x8*)&WT2[(size_t)(colb + 48) * 512 + ks * 32 + l16 * 8];
    acc0 = __builtin_amdgcn_mfma_f32_16x16x32_bf16(a, b0, acc0, 0, 0, 0);
    acc1 = __builtin_amdgcn_mfma_f32_16x16x32_bf16(a, b1, acc1, 0, 0, 0);
    acc2 = __builtin_amdgcn_mfma_f32_16x16x32_bf16(a, b2, acc2, 0, 0, 0);
    acc3 = __builtin_amdgcn_mfma_f32_16x16x32_bf16(a, b3, acc3, 0, 0, 0);
  }
  #pragma unroll
  for (int tt = 0; tt < 4; tt++) {
    const f32x4* ap = (tt == 0) ? &acc0 : (tt == 1) ? &acc1 : (tt == 2) ? &acc2 : &acc3;
    int col = wave * 64 + tt * 16 + l15;
    float bv = (col < 128) ? bl[col] : br[col - 128];
    float* outp = (col < 128) ? xl : xr;
    int cc = (col < 128) ? col : col - 128;
    #pragma unroll
    for (int r = 0; r < 4; r++)
      outp[(size_t)(n0 + l16 * 4 + r) * HID + cc] = (*ap)[r] + bv;
  }
}

// ---------------- fused layer 2 (16-edge chunks; bf16 ee) ----------------
// block = 512 threads = 8 waves = 8 nodes. lane owns channels {2*lane, 2*lane+1}.
// One chunk covers 16 edges: all MFMA columns real.
__global__ __launch_bounds__(512, 2) void fused2_kernel(
    const float* __restrict__ ea, const int* __restrict__ srcs,
    const float* __restrict__ We, const float* __restrict__ att,
    const float* __restrict__ xl, const float* __restrict__ xr,
    const float* __restrict__ bias, const int* __restrict__ offs,
    const int* __restrict__ csr, float* __restrict__ h2out)
{
  __shared__ short W2tT[HID * 40];       // 10KB
  __shared__ short easb2[8][16 * 40];    // 10KB, all 16 rows real
  __shared__ short ee2b[8][16][136];     // 34.8KB: 16 edges x 128ch bf16 (+pad)
  int t = threadIdx.x;
  for (int i = t; i < EDGE_DIM * HID; i += 512) {
    int k = i >> 7, c = i & 127;
    W2tT[c * 40 + k] = (short)f2b(We[(size_t)k * HID + c]);
  }
  __syncthreads();
  int wave = t >> 6, lane = t & 63;
  int l15 = lane & 15, l16 = lane >> 4;
  int n = blockIdx.x * 8 + wave;
  int c = lane * 2;
  float2 atv = *(const float2*)&att[c];
  float2 xrv = *(const float2*)&xr[(size_t)n * HID + c];
  float oa = 0.f, ob = 0.f;
  float m = 8.0f, d = 0.f;
  int beg = offs[n], end = offs[n + 1];
  int ev = 0, sv = 0;
  if (lane < 16 && beg + lane < end) { ev = csr[beg + lane]; sv = srcs[ev]; }
  for (int i0 = beg; i0 < end; i0 += 16) {
    int nv = end - i0; if (nv > 16) nv = 16;
    int sarr[16];
    #pragma unroll
    for (int j = 0; j < 16; j++) sarr[j] = __shfl(sv, j);
    // xl gathers issued first (float2/lane, coalesced)
    float2 xv[16];
    #pragma unroll
    for (int j = 0; j < 16; j++) {
      if (j < nv) xv[j] = *(const float2*)&xl[(size_t)sarr[j] * HID + c];
      else { xv[j].x = 0.f; xv[j].y = 0.f; }
    }
    // stage 16 ea rows as bf16 (all 64 lanes: edge=lane>>2, quarter q=lane&3)
    {
      int me = __shfl(ev, lane >> 2);
      int q = lane & 3;
      float4 u0 = *(const float4*)&ea[(size_t)me * EDGE_DIM + q * 8];
      float4 u1 = *(const float4*)&ea[(size_t)me * EDGE_DIM + q * 8 + 4];
      short* dst = &easb2[wave][(lane >> 2) * 40 + q * 8];
      dst[0] = (short)f2b(u0.x); dst[1] = (short)f2b(u0.y);
      dst[2] = (short)f2b(u0.z); dst[3] = (short)f2b(u0.w);
      dst[4] = (short)f2b(u1.x); dst[5] = (short)f2b(u1.y);
      dst[6] = (short)f2b(u1.z); dst[7] = (short)f2b(u1.w);
    }
    // prefetch next chunk's indices
    if (lane < 16 && i0 + 16 + lane < end) { ev = csr[i0 + 16 + lane]; sv = srcs[ev]; }
    // 8 MFMAs, all 16 edge columns real
    bf16x8 bfrag = *(bf16x8*)&easb2[wave][l15 * 40 + l16 * 8];
    #pragma unroll 4
    for (int tt = 0; tt < 8; tt++) {
      bf16x8 afrag = *(bf16x8*)&W2tT[(tt * 16 + l15) * 40 + l16 * 8];
      f32x4 cz = {0.f, 0.f, 0.f, 0.f};
      f32x4 cv = __builtin_amdgcn_mfma_f32_16x16x32_bf16(afrag, bfrag, cz, 0, 0, 0);
      ushort4 u;
      u.x = f2b(cv[0]); u.y = f2b(cv[1]); u.z = f2b(cv[2]); u.w = f2b(cv[3]);
      *(ushort4*)&ee2b[wave][l15][tt * 16 + l16 * 4] = u;
    }
    // tail: 16 independent 64-lane butterflies; defer-max softmax
    float pl[16];
    #pragma unroll
    for (int j = 0; j < 16; j++) {
      ushort2 uv = *(const ushort2*)&ee2b[wave][j][c];
      float za = b2f(uv.x) + xv[j].x + xrv.x;
      float zb = b2f(uv.y) + xv[j].y + xrv.y;
      za = za > 0.f ? za : NEG_SLOPE * za;
      zb = zb > 0.f ? zb : NEG_SLOPE * zb;
      float s = za * atv.x + zb * atv.y;
      #pragma unroll
      for (int o = 1; o < 64; o <<= 1) s += __shfl_xor(s, o);
      pl[j] = (j < nv) ? s : -3.0e38f;
    }
    float cm = pl[0];
    #pragma unroll
    for (int j = 1; j < 16; j++) cm = fmaxf(cm, pl[j]);
    float mn = fmaxf(m, cm);
    if (__any(mn > m + 8.f)) {
      float fs = __expf(m - mn);
      d *= fs; oa *= fs; ob *= fs;
      m = mn;
    }
    #pragma unroll
    for (int j = 0; j < 16; j++) {
      float p = __expf(pl[j] - m);
      d += p;
      oa = fmaf(p, xv[j].x, oa);
      ob = fmaf(p, xv[j].y, ob);
    }
  }
  float invd = d > 0.f ? 1.f / d : 0.f;
  float2 o2 = make_float2(oa * invd + bias[c], ob * invd + bias[c + 1]); // no relu after conv2
  *(float2*)&h2out[(size_t)n * HID + c] = o2;
}

// ---------------- MLP head ----------------
__global__ __launch_bounds__(256) void head_kernel(
    const float* __restrict__ h2, const float* __restrict__ Wh1,
    const float* __restrict__ bh1, const float* __restrict__ Wh2,
    const float* __restrict__ bh2, float* __restrict__ out)
{
  __shared__ float hs[16][HID];   // 8KB
  __shared__ float ts[16][64];    // 4KB
  int n0 = blockIdx.x * 16;
  int t = threadIdx.x;
  for (int r = 0; r < 2; r++) {
    int flat = (t + r * 256) * 4; // 2048 floats
    int i = flat >> 7, k = flat & 127;
    *(float4*)&hs[i][k] = *(const float4*)&h2[(size_t)(n0 + i) * HID + k];
  }
  __syncthreads();
  int j = t & 63, g = t >> 6;
  float acc[4];
  #pragma unroll
  for (int q = 0; q < 4; q++) acc[q] = 0.f;
  for (int k = 0; k < HID; k++) {
    float w = Wh1[k * 64 + j];
    #pragma unroll
    for (int q = 0; q < 4; q++) acc[q] = fmaf(hs[g + 4 * q][k], w, acc[q]);
  }
  float bj = bh1[j];
  #pragma unroll
  for (int q = 0; q < 4; q++) {
    float v = acc[q] + bj;
    ts[g + 4 * q][j] = v > 0.f ? v : 0.f;
  }
  __syncthreads();
  if (t < 32) {
    int nl = t >> 1, k = t & 1;
    float acc2 = bh2[k];
    for (int jj = 0; jj < 64; jj++) acc2 = fmaf(ts[nl][jj], Wh2[jj * 2 + k], acc2);
    out[(size_t)(n0 + nl) * 2 + k] = acc2;
  }
}

extern "C" void kernel_launch(void* const* d_in, const int* in_sizes, int n_in,
                              void* d_out, int out_size, void* d_ws, size_t ws_size,
                              hipStream_t stream)
{
  (void)in_sizes; (void)n_in; (void)out_size;
  const float* x    = (const float*)d_in[0];
  const int* eidx   = (const int*)d_in[1];
  const float* ea   = (const float*)d_in[2];
  const float* Wl1  = (const float*)d_in[3];
  const float* bl1  = (const float*)d_in[4];
  const float* Wr1  = (const float*)d_in[5];
  const float* br1  = (const float*)d_in[6];
  const float* We1  = (const float*)d_in[7];
  const float* att1 = (const float*)d_in[8];
  const float* bias1= (const float*)d_in[9];
  const float* Wl2  = (const float*)d_in[10];
  const float* bl2  = (const float*)d_in[11];
  const float* Wr2  = (const float*)d_in[12];
  const float* br2  = (const float*)d_in[13];
  const float* We2  = (const float*)d_in[14];
  const float* att2 = (const float*)d_in[15];
  const float* bias2= (const float*)d_in[16];
  const float* Wh1  = (const float*)d_in[17];
  const float* bh1  = (const float*)d_in[18];
  const float* Wh2  = (const float*)d_in[19];
  const float* bh2  = (const float*)d_in[20];
  const int* srcs = eidx;
  const int* dsts = eidx + N_EDGES;
  float* out = (float*)d_out;

  const size_t szBig = (size_t)N_NODES * HC1 * sizeof(float);
  auto aln = [](size_t b) { return (b + 511) & ~(size_t)511; };
  size_t smallSz = aln((size_t)N_NODES * 4) * 2 + aln((size_t)(N_NODES + 1) * 4)
                 + aln((size_t)N_EDGES * 4) + aln(1024 * 64 * 2) + aln(256 * 512 * 2);
  size_t needF = aln(szBig) * 3 + smallSz + 4096;
  bool useBF = ws_size < needF;

  char* p = (char*)d_ws;
  auto alloc = [&](size_t bytes) { char* q = p; p += (bytes + 511) & ~(size_t)511; return q; };
  float* xl1 = (float*)alloc(szBig);
  float* xr1 = (float*)alloc(szBig);          // reused for xl2/xr2 after fused1
  void*  h1  = (void*)alloc(useBF ? szBig / 2 : szBig);
  int* deg    = (int*)alloc((size_t)N_NODES * 4);
  int* offs   = (int*)alloc((size_t)(N_NODES + 1) * 4);
  int* cursor = (int*)alloc((size_t)N_NODES * 4);
  int* csr    = (int*)alloc((size_t)N_EDGES * 4);
  unsigned short* WT1 = (unsigned short*)alloc(1024 * 64 * 2);
  unsigned short* WT2 = (unsigned short*)alloc(256 * 512 * 2);
  float* xl2 = xr1;
  float* xr2 = xr1 + (size_t)N_NODES * HID;
  float* h2  = xl1;                            // xl1 region dead after fused1

  hipMemsetAsync(deg, 0, (size_t)N_NODES * 4, stream);
  hipLaunchKernelGGL(deg_count_kernel, dim3((N_EDGES + 255) / 256), dim3(256), 0, stream, dsts, deg);
  hipLaunchKernelGGL(wconv_kernel, dim3(512), dim3(256), 0, stream, Wl1, Wr1, Wl2, Wr2, WT1, WT2);
  hipLaunchKernelGGL(scan_kernel, dim3(1), dim3(1024), 0, stream, deg, offs, cursor);
  hipLaunchKernelGGL(scatter_kernel, dim3((N_EDGES + 255) / 256), dim3(256), 0, stream, dsts, cursor, csr);
  hipLaunchKernelGGL(linear1_kernel, dim3(N_NODES / 16), dim3(256), 0, stream,
                     x, WT1, bl1, br1, xl1, xr1);
  // fused1: grid = (N/8 node-groups) x 2 halves
  if (useBF)
    hipLaunchKernelGGL((fused1_kernel<true>), dim3((N_NODES / 8) * 2), dim3(512), 0, stream,
                       ea, srcs, We1, att1, xl1, xr1, bias1, offs, csr, h1);
  else
    hipLaunchKernelGGL((fused1_kernel<false>), dim3((N_NODES / 8) * 2), dim3(512), 0, stream,
                       ea, srcs, We1, att1, xl1, xr1, bias1, offs, csr, h1);
  if (useBF)
    hipLaunchKernelGGL((linear2_kernel<true>), dim3(N_NODES / 16), dim3(256), 0, stream,
                       h1, WT2, bl2, br2, xl2, xr2);
  else
    hipLaunchKernelGGL((linear2_kernel<false>), dim3(N_NODES / 16), dim3(256), 0, stream,
                       h1, WT2, bl2, br2, xl2, xr2);
  hipLaunchKernelGGL(fused2_kernel, dim3(N_NODES / 8), dim3(512), 0, stream,
                     ea, srcs, We2, att2, xl2, xr2, bias2, offs, csr, h2);
  hipLaunchKernelGGL(head_kernel, dim3(N_NODES / 16), dim3(256), 0, stream,
                     h2, Wh1, bh1, Wh2, bh2, out);
}